// Round 6
// baseline (235.120 us; speedup 1.0000x reference)
//
#include <hip/hip_runtime.h>
#include <math.h>

#define S_LEN 2048
#define BATCH 2
#define DMODEL 1024
#define NHEADS 16
#define MROWS 4096

typedef short bf8 __attribute__((ext_vector_type(8)));   // 8 x bf16 (4 VGPRs)
typedef float f32x4 __attribute__((ext_vector_type(4))); // MFMA accumulator
typedef unsigned short u16;

static __device__ inline u16 f2bf(float f) {
    union { float f; unsigned u; } v; v.f = f;
    unsigned r = v.u + 0x7fffu + ((v.u >> 16) & 1u); // RNE
    return (u16)(r >> 16);
}

// async global->LDS DMA, 16B per lane. LDS dest = (wave-uniform base) + lane*16.
static __device__ inline void load16(const void* g, void* l) {
    __builtin_amdgcn_global_load_lds(
        (const __attribute__((address_space(1))) unsigned int*)g,
        (__attribute__((address_space(3))) unsigned int*)l, 16, 0, 0);
}

// ---------------------------------------------------------------------------
// fp32 -> bf16, 8 elems/thread.
// ---------------------------------------------------------------------------
__global__ __launch_bounds__(256) void convert_kernel(const float* __restrict__ in,
                                                      u16* __restrict__ out) {
    int i = blockIdx.x * 256 + threadIdx.x;
    const float4* p = (const float4*)in + (size_t)i * 2;
    float4 a = p[0], b = p[1];
    u16 tmp[8] = {f2bf(a.x), f2bf(a.y), f2bf(a.z), f2bf(a.w),
                  f2bf(b.x), f2bf(b.y), f2bf(b.z), f2bf(b.w)};
    ((uint4*)out)[i] = *(uint4*)tmp;
}

// ---------------------------------------------------------------------------
// W [1024][1024] fp32 -> Wt [n][k] bf16. blockIdx.z picks which W.
// ---------------------------------------------------------------------------
__global__ __launch_bounds__(256) void transpose_w_kernel(
    const float* __restrict__ W0, const float* __restrict__ W1,
    const float* __restrict__ W2, const float* __restrict__ W3,
    u16* __restrict__ out) {
    __shared__ u16 Ls[64][65];
    const float* W = blockIdx.z == 0 ? W0 : blockIdx.z == 1 ? W1
                   : blockIdx.z == 2 ? W2 : W3;
    u16* Wt = out + (size_t)blockIdx.z * 1024 * 1024;
    int t = threadIdx.x, r = t >> 2, c4 = (t & 3) * 16;
    int k0 = blockIdx.y * 64, n0 = blockIdx.x * 64;
    const float* p = W + (size_t)(k0 + r) * 1024 + n0 + c4;
#pragma unroll
    for (int i = 0; i < 16; i += 4) {
        float4 v = *(const float4*)(p + i);
        Ls[r][c4 + i + 0] = f2bf(v.x);
        Ls[r][c4 + i + 1] = f2bf(v.y);
        Ls[r][c4 + i + 2] = f2bf(v.z);
        Ls[r][c4 + i + 3] = f2bf(v.w);
    }
    __syncthreads();
    u16 tmp[16];
#pragma unroll
    for (int i = 0; i < 16; i++) tmp[i] = Ls[c4 + i][r];
    uint4* q = (uint4*)(Wt + (size_t)(n0 + r) * 1024 + k0 + c4);
    q[0] = *(uint4*)tmp;
    q[1] = *(uint4*)(tmp + 8);
}

// ---------------------------------------------------------------------------
// m97-recipe GEMM: C = A[4096,1024](bf16) @ Bt[N,1024](bf16)^T (+bias)
// 128x128 tile, BK=32, global_load_lds(16B) into unpadded [128][32] LDS,
// 4 waves each computing a 64x64 quadrant (4x4 f32x4 acc, 16 MFMA/iter).
// MODE 0: fused QKV (N=3072; sect 0->Q bf16*qscale, 1->K bf16, 2->V^T bf16)
// MODE 1: O-proj    (N=1024; fp32 row-major + bias)
// ---------------------------------------------------------------------------
template <int MODE>
__global__ __launch_bounds__(256) void gemm_mfma(
    const u16* __restrict__ A, const u16* __restrict__ Bt,
    const float* __restrict__ bqp, const float* __restrict__ bkp,
    const float* __restrict__ bvp,
    u16* __restrict__ qout, u16* __restrict__ kout, u16* __restrict__ vtout,
    float* __restrict__ fout, float qscale) {
    __shared__ __align__(16) u16 As[128 * 32];
    __shared__ __align__(16) u16 Bs[128 * 32];

    const int t = threadIdx.x, lane = t & 63, w = t >> 6;
    const int quad = lane >> 4, l16 = lane & 15;
    const int row0 = blockIdx.y * 128, col0 = blockIdx.x * 128;
    const int wr = (w >> 1) * 64, wc = (w & 1) * 64;
    const int K = DMODEL;

    // staging: wave w owns rows [w*32, w*32+32) of both tiles; lane covers
    // row w*32 + i*16 + (lane>>2), elems (lane&3)*8 .. +8  (16B per lane)
    const int srow = w * 32 + (lane >> 2);
    const int koff = (lane & 3) * 8;
    const u16* ag = A + (size_t)(row0 + srow) * K + koff;
    const u16* bg = Bt + (size_t)(col0 + srow) * K + koff;
    u16* lA0 = As + (w * 32) * 32;
    u16* lA1 = As + (w * 32 + 16) * 32;
    u16* lB0 = Bs + (w * 32) * 32;
    u16* lB1 = Bs + (w * 32 + 16) * 32;
    const size_t r16 = (size_t)16 * K;

    f32x4 acc[4][4] = {};

    for (int k0 = 0; k0 < K; k0 += 32) {
        load16(ag + k0, lA0);
        load16(ag + r16 + k0, lA1);
        load16(bg + k0, lB0);
        load16(bg + r16 + k0, lB1);
        __syncthreads(); // drains vmcnt -> LDS valid
        bf8 af[4], bfr[4];
#pragma unroll
        for (int mi = 0; mi < 4; mi++)
            af[mi] = *(const bf8*)&As[(wr + mi * 16 + l16) * 32 + quad * 8];
#pragma unroll
        for (int ni = 0; ni < 4; ni++)
            bfr[ni] = *(const bf8*)&Bs[(wc + ni * 16 + l16) * 32 + quad * 8];
#pragma unroll
        for (int mi = 0; mi < 4; mi++)
#pragma unroll
            for (int ni = 0; ni < 4; ni++)
                acc[mi][ni] = __builtin_amdgcn_mfma_f32_16x16x32_bf16(
                    af[mi], bfr[ni], acc[mi][ni], 0, 0, 0);
        __syncthreads(); // all reads done before next iter's DMA overwrites
    }

#pragma unroll
    for (int mi = 0; mi < 4; mi++) {
        const int r = row0 + wr + mi * 16 + quad * 4;
#pragma unroll
        for (int ni = 0; ni < 4; ni++) {
            const int c = col0 + wc + ni * 16 + l16;
            if (MODE == 1) {
                float bvv = bqp[c];
#pragma unroll
                for (int reg = 0; reg < 4; reg++)
                    fout[(size_t)(r + reg) * 1024 + c] = acc[mi][ni][reg] + bvv;
            } else {
                const int sect = c >> 10, cl = c & 1023;
                const float* bp = sect == 0 ? bqp : sect == 1 ? bkp : bvp;
                float bvv = bp[cl];
                if (sect == 0) {
#pragma unroll
                    for (int reg = 0; reg < 4; reg++)
                        qout[(size_t)(r + reg) * 1024 + cl] =
                            f2bf((acc[mi][ni][reg] + bvv) * qscale);
                } else if (sect == 1) {
#pragma unroll
                    for (int reg = 0; reg < 4; reg++)
                        kout[(size_t)(r + reg) * 1024 + cl] =
                            f2bf(acc[mi][ni][reg] + bvv);
                } else { // V^T: Vt[(r>>11)*1024 + cl][r&2047 .. +3]
                    u16 t4[4];
#pragma unroll
                    for (int reg = 0; reg < 4; reg++)
                        t4[reg] = f2bf(acc[mi][ni][reg] + bvv);
                    *(uint2*)(vtout + ((size_t)(r >> 11) * 1024 + cl) * S_LEN +
                              (r & 2047)) = *(uint2*)t4;
                }
            }
        }
    }
}

// ---------------------------------------------------------------------------
// Flash attention, causal, no-max softmax via exp2 (log2e*scale folded into Q).
// 128-query blocks, 4 waves x 32 queries. Two-plane [2][64][32] K/V LDS
// (m97-style banking: conflict-light b128 frag reads). Truncating P pack.
// ---------------------------------------------------------------------------
__global__ __launch_bounds__(256) void attn_kernel(const u16* __restrict__ Qg,
                                                   const u16* __restrict__ Kg,
                                                   const u16* __restrict__ Vt,
                                                   u16* __restrict__ Og) {
    __shared__ __align__(16) u16 Ks[2][64][32];  // [d-half][key][d%32]
    __shared__ __align__(16) u16 Vs[2][64][32];  // [key-half][d][key%32]
    __shared__ __align__(16) u16 Ps[4][32][72];  // per-wave P (32 queries)

    const int t = threadIdx.x, lane = t & 63, w = t >> 6;
    const int quad = lane >> 4, l16 = lane & 15;
    const int qi = gridDim.x - 1 - blockIdx.x; // longest blocks dispatch first
    const int bh = blockIdx.y, b = bh >> 4, h = bh & 15;
    const size_t base = (size_t)b * S_LEN * DMODEL + h * 64;
    const size_t vbase = ((size_t)b * 1024 + h * 64) * S_LEN;
    const int q0 = qi * 128;
    const int sr = t >> 2, sc = (t & 3) * 16;
    const int p0 = sc >> 5, c0 = sc & 31;          // plane/col for first uint4
    const int p1 = (sc + 8) >> 5, c1 = (sc + 8) & 31;

    bf8 aq[2][2];
#pragma unroll
    for (int mg = 0; mg < 2; mg++)
#pragma unroll
        for (int c = 0; c < 2; c++)
            aq[mg][c] = *(const bf8*)(Qg + base +
                (size_t)(q0 + w * 32 + mg * 16 + l16) * DMODEL + c * 32 + quad * 8);

    float lsum[2][4] = {};
    f32x4 o_acc[2][4] = {};
    const int ktl = 2 * qi + 1;

    const u16* kp = Kg + base + (size_t)sr * DMODEL + sc;
    const u16* vp = Vt + vbase + (size_t)sr * S_LEN + sc;
    uint4 k0r = *(const uint4*)kp, k1r = *(const uint4*)(kp + 8);
    uint4 v0r = *(const uint4*)vp, v1r = *(const uint4*)(vp + 8);

    for (int kt = 0; kt <= ktl; kt++) {
        __syncthreads();
        *(uint4*)&Ks[p0][sr][c0] = k0r; *(uint4*)&Ks[p1][sr][c1] = k1r;
        *(uint4*)&Vs[p0][sr][c0] = v0r; *(uint4*)&Vs[p1][sr][c1] = v1r;
        __syncthreads();
        if (kt < ktl) { // prefetch next K/V tile during compute
            size_t ok = (size_t)(kt + 1) * 64 * DMODEL;
            int ov = (kt + 1) * 64;
            k0r = *(const uint4*)(kp + ok); k1r = *(const uint4*)(kp + ok + 8);
            v0r = *(const uint4*)(vp + ov); v1r = *(const uint4*)(vp + ov + 8);
        }

        // S = Q K^T: 32q x 64key per wave (B-frags shared across both q-groups)
        f32x4 scv[2][4] = {};
#pragma unroll
        for (int c = 0; c < 2; c++)
#pragma unroll
            for (int ns = 0; ns < 4; ns++) {
                bf8 bk = *(const bf8*)&Ks[c][ns * 16 + l16][quad * 8];
                scv[0][ns] = __builtin_amdgcn_mfma_f32_16x16x32_bf16(aq[0][c], bk, scv[0][ns], 0, 0, 0);
                scv[1][ns] = __builtin_amdgcn_mfma_f32_16x16x32_bf16(aq[1][c], bk, scv[1][ns], 0, 0, 0);
            }

        // exp2 (scale*log2e folded into Q); mask only the last two tiles
        const bool masked = (kt >= 2 * qi);
#pragma unroll
        for (int mg = 0; mg < 2; mg++) {
            const int myq = q0 + w * 32 + mg * 16 + quad * 4;
#pragma unroll
            for (int ns = 0; ns < 4; ns++) {
                int key = kt * 64 + ns * 16 + l16;
#pragma unroll
                for (int r = 0; r < 4; r++) {
                    float p = (masked && key > myq + r)
                                  ? 0.f
                                  : __builtin_amdgcn_exp2f(scv[mg][ns][r]);
                    lsum[mg][r] += p;
                    Ps[w][mg * 16 + quad * 4 + r][ns * 16 + l16] =
                        (u16)(__float_as_uint(p) >> 16); // trunc pack
                }
            }
        }
        asm volatile("s_waitcnt lgkmcnt(0)" ::: "memory"); // same-wave LDS W->R

        // O += P @ V (V-frags shared across both q-groups)
#pragma unroll
        for (int kc = 0; kc < 2; kc++) {
            bf8 ap0 = *(const bf8*)&Ps[w][l16][kc * 32 + quad * 8];
            bf8 ap1 = *(const bf8*)&Ps[w][16 + l16][kc * 32 + quad * 8];
#pragma unroll
            for (int ds = 0; ds < 4; ds++) {
                bf8 bvv = *(const bf8*)&Vs[kc][ds * 16 + l16][quad * 8];
                o_acc[0][ds] = __builtin_amdgcn_mfma_f32_16x16x32_bf16(ap0, bvv, o_acc[0][ds], 0, 0, 0);
                o_acc[1][ds] = __builtin_amdgcn_mfma_f32_16x16x32_bf16(ap1, bvv, o_acc[1][ds], 0, 0, 0);
            }
        }
    }

    // epilogue: reduce l across the 16 key-lanes, normalize, store
#pragma unroll
    for (int mg = 0; mg < 2; mg++)
#pragma unroll
        for (int r = 0; r < 4; r++) {
            float l = lsum[mg][r];
#pragma unroll
            for (int off = 8; off >= 1; off >>= 1) l += __shfl_xor(l, off, 64);
            float inv = 1.f / l;
            int qq = q0 + w * 32 + mg * 16 + quad * 4 + r;
#pragma unroll
            for (int ds = 0; ds < 4; ds++)
                Og[base + (size_t)qq * DMODEL + ds * 16 + l16] = f2bf(o_acc[mg][ds][r] * inv);
        }
}

// ---------------------------------------------------------------------------
// Workspace: d_ws 32MB = wT(8) | qb(8) | kb(8) | ob(8).
// Transients xb/vt live inside d_out (16MB), dead before O-proj writes it.
// ---------------------------------------------------------------------------
extern "C" void kernel_launch(void* const* d_in, const int* in_sizes, int n_in,
                              void* d_out, int out_size, void* d_ws, size_t ws_size,
                              hipStream_t stream) {
    const float* x  = (const float*)d_in[0];
    const float* wq = (const float*)d_in[1];
    const float* bq = (const float*)d_in[2];
    const float* wk = (const float*)d_in[3];
    const float* bk = (const float*)d_in[4];
    const float* wv = (const float*)d_in[5];
    const float* bv = (const float*)d_in[6];
    const float* wo = (const float*)d_in[7];
    const float* bo = (const float*)d_in[8];
    float* out = (float*)d_out;

    const size_t E = (size_t)MROWS * DMODEL; // 4M elems
    u16* xb  = (u16*)d_out;      // bf16 x (dead after QKV GEMM)
    u16* vt  = xb + E;           // V^T (dead after attn)
    u16* wT  = (u16*)d_ws;       // wqT|wkT|wvT|woT, 4 x 1M elems
    u16* woT = wT + 3145728;
    u16* qb  = wT + 4194304;
    u16* kb  = qb + E;
    u16* ob  = kb + E;

    dim3 blk(256);
    convert_kernel<<<2048, blk, 0, stream>>>(x, xb);
    transpose_w_kernel<<<dim3(16, 16, 4), blk, 0, stream>>>(wq, wk, wv, wo, wT);

    // fused QKV: N=3072 (Bt rows 0..3071 = wqT|wkT|wvT), Q scale = log2e/8
    gemm_mfma<0><<<dim3(24, 32), blk, 0, stream>>>(
        xb, wT, bq, bk, bv, qb, kb, vt, nullptr, 0.18033688011112042f);

    dim3 agrid(S_LEN / 128, BATCH * NHEADS); // (16, 32)
    attn_kernel<<<agrid, blk, 0, stream>>>(qb, kb, vt, ob);

    // O-proj: N=1024, fp32 out
    gemm_mfma<1><<<dim3(8, 32), blk, 0, stream>>>(
        ob, woT, bo, nullptr, nullptr, nullptr, nullptr, nullptr, out, 1.0f);
}

// Round 7
// 210.978 us; speedup vs baseline: 1.1144x; 1.1144x over previous
//
#include <hip/hip_runtime.h>
#include <math.h>

#define S_LEN 2048
#define BATCH 2
#define DMODEL 1024
#define NHEADS 16
#define MROWS 4096

typedef short bf8 __attribute__((ext_vector_type(8)));   // 8 x bf16 (4 VGPRs)
typedef float f32x4 __attribute__((ext_vector_type(4))); // MFMA accumulator
typedef unsigned short u16;

static __device__ inline u16 f2bf(float f) {
    union { float f; unsigned u; } v; v.f = f;
    unsigned r = v.u + 0x7fffu + ((v.u >> 16) & 1u); // RNE
    return (u16)(r >> 16);
}

// async global->LDS DMA, 16B per lane. LDS dest = (wave-uniform base) + lane*16.
static __device__ inline void load16(const void* g, void* l) {
    __builtin_amdgcn_global_load_lds(
        (const __attribute__((address_space(1))) unsigned int*)g,
        (__attribute__((address_space(3))) unsigned int*)l, 16, 0, 0);
}

// ---------------------------------------------------------------------------
// Fused prep: blocks [0,2048) convert x fp32->bf16 (8 elems/thread);
// blocks [2048,3072) transpose the 4 weights to Wt[n][k] bf16.
// ---------------------------------------------------------------------------
__global__ __launch_bounds__(256) void prep_kernel(
    const float* __restrict__ x, u16* __restrict__ xb,
    const float* __restrict__ W0, const float* __restrict__ W1,
    const float* __restrict__ W2, const float* __restrict__ W3,
    u16* __restrict__ wT) {
    const int bx = blockIdx.x, t = threadIdx.x;
    if (bx < 2048) {
        int i = bx * 256 + t;
        const float4* p = (const float4*)x + (size_t)i * 2;
        float4 a = p[0], b = p[1];
        u16 tmp[8] = {f2bf(a.x), f2bf(a.y), f2bf(a.z), f2bf(a.w),
                      f2bf(b.x), f2bf(b.y), f2bf(b.z), f2bf(b.w)};
        ((uint4*)xb)[i] = *(uint4*)tmp;
        return;
    }
    __shared__ u16 Ls[64][65];
    const int id = bx - 2048;
    const int z = id >> 8, rem = id & 255;
    const int n0 = (rem & 15) * 64, k0 = (rem >> 4) * 64;
    const float* W = z == 0 ? W0 : z == 1 ? W1 : z == 2 ? W2 : W3;
    u16* Wt = wT + (size_t)z * 1024 * 1024;
    const int r = t >> 2, c4 = (t & 3) * 16;
    const float* p = W + (size_t)(k0 + r) * 1024 + n0 + c4;
#pragma unroll
    for (int i = 0; i < 16; i += 4) {
        float4 v = *(const float4*)(p + i);
        Ls[r][c4 + i + 0] = f2bf(v.x);
        Ls[r][c4 + i + 1] = f2bf(v.y);
        Ls[r][c4 + i + 2] = f2bf(v.z);
        Ls[r][c4 + i + 3] = f2bf(v.w);
    }
    __syncthreads();
    u16 tmp[16];
#pragma unroll
    for (int i = 0; i < 16; i++) tmp[i] = Ls[c4 + i][r];
    uint4* q = (uint4*)(Wt + (size_t)(n0 + r) * 1024 + k0 + c4);
    q[0] = *(uint4*)tmp;
    q[1] = *(uint4*)(tmp + 8);
}

// ---------------------------------------------------------------------------
// m97-recipe GEMM: C = A[4096,1024](bf16) @ Bt[N,1024](bf16)^T (+bias)
// 128x128 tile, BK=32, global_load_lds(16B) into unpadded [128][32] LDS,
// 4 waves each computing a 64x64 quadrant (4x4 f32x4 acc, 16 MFMA/iter).
// MODE 0: fused QKV (N=3072; sect 0->Q bf16*qscale, 1->K bf16, 2->V^T bf16)
// MODE 1: O-proj    (N=1024; fp32 row-major + bias)
// ---------------------------------------------------------------------------
template <int MODE>
__global__ __launch_bounds__(256) void gemm_mfma(
    const u16* __restrict__ A, const u16* __restrict__ Bt,
    const float* __restrict__ bqp, const float* __restrict__ bkp,
    const float* __restrict__ bvp,
    u16* __restrict__ qout, u16* __restrict__ kout, u16* __restrict__ vtout,
    float* __restrict__ fout, float qscale) {
    __shared__ __align__(16) u16 As[128 * 32];
    __shared__ __align__(16) u16 Bs[128 * 32];

    const int t = threadIdx.x, lane = t & 63, w = t >> 6;
    const int quad = lane >> 4, l16 = lane & 15;
    const int row0 = blockIdx.y * 128, col0 = blockIdx.x * 128;
    const int wr = (w >> 1) * 64, wc = (w & 1) * 64;
    const int K = DMODEL;

    const int srow = w * 32 + (lane >> 2);
    const int koff = (lane & 3) * 8;
    const u16* ag = A + (size_t)(row0 + srow) * K + koff;
    const u16* bg = Bt + (size_t)(col0 + srow) * K + koff;
    u16* lA0 = As + (w * 32) * 32;
    u16* lA1 = As + (w * 32 + 16) * 32;
    u16* lB0 = Bs + (w * 32) * 32;
    u16* lB1 = Bs + (w * 32 + 16) * 32;
    const size_t r16 = (size_t)16 * K;

    f32x4 acc[4][4] = {};

    for (int k0 = 0; k0 < K; k0 += 32) {
        load16(ag + k0, lA0);
        load16(ag + r16 + k0, lA1);
        load16(bg + k0, lB0);
        load16(bg + r16 + k0, lB1);
        __syncthreads(); // drains vmcnt -> LDS valid
        bf8 af[4], bfr[4];
#pragma unroll
        for (int mi = 0; mi < 4; mi++)
            af[mi] = *(const bf8*)&As[(wr + mi * 16 + l16) * 32 + quad * 8];
#pragma unroll
        for (int ni = 0; ni < 4; ni++)
            bfr[ni] = *(const bf8*)&Bs[(wc + ni * 16 + l16) * 32 + quad * 8];
#pragma unroll
        for (int mi = 0; mi < 4; mi++)
#pragma unroll
            for (int ni = 0; ni < 4; ni++)
                acc[mi][ni] = __builtin_amdgcn_mfma_f32_16x16x32_bf16(
                    af[mi], bfr[ni], acc[mi][ni], 0, 0, 0);
        __syncthreads(); // all reads done before next iter's DMA overwrites
    }

    const int sect = (col0 + wc) >> 10; // uniform per wave (64-aligned spans)
#pragma unroll
    for (int mi = 0; mi < 4; mi++) {
        const int r = row0 + wr + mi * 16 + quad * 4;
#pragma unroll
        for (int ni = 0; ni < 4; ni++) {
            const int c = col0 + wc + ni * 16 + l16;
            if (MODE == 1) {
                float bvv = bqp[c];
#pragma unroll
                for (int reg = 0; reg < 4; reg++)
                    fout[(size_t)(r + reg) * 1024 + c] = acc[mi][ni][reg] + bvv;
            } else {
                const int cl = c & 1023;
                const float* bp = sect == 0 ? bqp : sect == 1 ? bkp : bvp;
                float bvv = bp[cl];
                if (sect == 0) {
#pragma unroll
                    for (int reg = 0; reg < 4; reg++)
                        qout[(size_t)(r + reg) * 1024 + cl] =
                            f2bf((acc[mi][ni][reg] + bvv) * qscale);
                } else if (sect == 1) {
#pragma unroll
                    for (int reg = 0; reg < 4; reg++)
                        kout[(size_t)(r + reg) * 1024 + cl] =
                            f2bf(acc[mi][ni][reg] + bvv);
                } else { // V^T: Vt[(r>>11)*1024 + cl][r&2047 .. +3]
                    u16 t4[4];
#pragma unroll
                    for (int reg = 0; reg < 4; reg++)
                        t4[reg] = f2bf(acc[mi][ni][reg] + bvv);
                    *(uint2*)(vtout + ((size_t)(r >> 11) * 1024 + cl) * S_LEN +
                              (r & 2047)) = *(uint2*)t4;
                }
            }
        }
    }
}

// ---------------------------------------------------------------------------
// Flash attention, causal, no-max softmax via exp2 (log2e*scale folded in Q).
// Paired q-tiles for uniform load: block (pi,bh) does tiles pi and 31-pi
// (64 queries each) -> exactly 33 k-iters per block. 4 waves x 16 queries.
// Two-plane LDS for K/V and per-wave P (conflict-free b128 frag reads).
// ---------------------------------------------------------------------------
__global__ __launch_bounds__(256) void attn_kernel(const u16* __restrict__ Qg,
                                                   const u16* __restrict__ Kg,
                                                   const u16* __restrict__ Vt,
                                                   u16* __restrict__ Og) {
    __shared__ __align__(16) u16 Ks[2][64][32];     // [d-half][key][d%32]
    __shared__ __align__(16) u16 Vs[2][64][32];     // [key-half][d][key%32]
    __shared__ __align__(16) u16 Ps[4][2][16][32];  // [wave][key-half][q][key%32]

    const int t = threadIdx.x, lane = t & 63, w = t >> 6;
    const int quad = lane >> 4, l16 = lane & 15;
    const int pi = blockIdx.x;
    const int bh = blockIdx.y, b = bh >> 4, h = bh & 15;
    const size_t base = (size_t)b * S_LEN * DMODEL + h * 64;
    const size_t vbase = ((size_t)b * 1024 + h * 64) * S_LEN;
    const int sr = t >> 2, sc = (t & 3) * 16;
    const int p0 = sc >> 5, c0 = sc & 31;
    const int p1 = (sc + 8) >> 5, c1 = (sc + 8) & 31;

    const u16* kp = Kg + base + (size_t)sr * DMODEL + sc;
    const u16* vp = Vt + vbase + (size_t)sr * S_LEN + sc;
    uint4 k0r = *(const uint4*)kp, k1r = *(const uint4*)(kp + 8);
    uint4 v0r = *(const uint4*)vp, v1r = *(const uint4*)(vp + 8);

#pragma unroll
    for (int seg = 0; seg < 2; seg++) {
        const int qt = seg == 0 ? pi : 31 - pi;
        const int niter = qt + 1;
        const int q0 = qt * 64;

        bf8 aq[2];
#pragma unroll
        for (int c = 0; c < 2; c++)
            aq[c] = *(const bf8*)(Qg + base +
                (size_t)(q0 + w * 16 + l16) * DMODEL + c * 32 + quad * 8);

        float lsum[4] = {};
        f32x4 o_acc[4] = {};

        for (int kt = 0; kt < niter; kt++) {
            __syncthreads();
            *(uint4*)&Ks[p0][sr][c0] = k0r; *(uint4*)&Ks[p1][sr][c1] = k1r;
            *(uint4*)&Vs[p0][sr][c0] = v0r; *(uint4*)&Vs[p1][sr][c1] = v1r;
            __syncthreads();
            // prefetch next K/V tile (next kt, or tile 0 of segment B)
            if (!(seg == 1 && kt + 1 == niter)) {
                int nt = (kt + 1 < niter) ? kt + 1 : 0;
                size_t ok = (size_t)nt * 64 * DMODEL;
                int ov = nt * 64;
                k0r = *(const uint4*)(kp + ok); k1r = *(const uint4*)(kp + ok + 8);
                v0r = *(const uint4*)(vp + ov); v1r = *(const uint4*)(vp + ov + 8);
            }

            // S = Q K^T: 16q x 64key per wave
            f32x4 scv[4] = {};
#pragma unroll
            for (int c = 0; c < 2; c++)
#pragma unroll
                for (int ns = 0; ns < 4; ns++) {
                    bf8 bk = *(const bf8*)&Ks[c][ns * 16 + l16][quad * 8];
                    scv[ns] = __builtin_amdgcn_mfma_f32_16x16x32_bf16(
                        aq[c], bk, scv[ns], 0, 0, 0);
                }

            // exp2 (scale*log2e folded into Q); mask only the diagonal tile
            const bool diag = (kt == qt);
            const int myq = w * 16 + quad * 4;
#pragma unroll
            for (int ns = 0; ns < 4; ns++) {
                int key = ns * 16 + l16;
#pragma unroll
                for (int r = 0; r < 4; r++) {
                    float p = (diag && key > myq + r)
                                  ? 0.f
                                  : __builtin_amdgcn_exp2f(scv[ns][r]);
                    lsum[r] += p;
                    Ps[w][ns >> 1][quad * 4 + r][(ns & 1) * 16 + l16] =
                        (u16)(__float_as_uint(p) >> 16); // trunc pack
                }
            }
            asm volatile("s_waitcnt lgkmcnt(0)" ::: "memory"); // wave-private W->R

            // O += P @ V
#pragma unroll
            for (int kc = 0; kc < 2; kc++) {
                bf8 apv = *(const bf8*)&Ps[w][kc][l16][quad * 8];
#pragma unroll
                for (int ds = 0; ds < 4; ds++) {
                    bf8 bvv = *(const bf8*)&Vs[kc][ds * 16 + l16][quad * 8];
                    o_acc[ds] = __builtin_amdgcn_mfma_f32_16x16x32_bf16(
                        apv, bvv, o_acc[ds], 0, 0, 0);
                }
            }
        }

        // epilogue: reduce l across the 16 key-lanes, normalize, store
#pragma unroll
        for (int r = 0; r < 4; r++) {
            float l = lsum[r];
#pragma unroll
            for (int off = 8; off >= 1; off >>= 1) l += __shfl_xor(l, off, 64);
            float inv = 1.f / l;
            int qq = q0 + w * 16 + quad * 4 + r;
#pragma unroll
            for (int ds = 0; ds < 4; ds++)
                Og[base + (size_t)qq * DMODEL + ds * 16 + l16] =
                    f2bf(o_acc[ds][r] * inv);
        }
    }
}

// ---------------------------------------------------------------------------
// Workspace: d_ws 32MB = wT(8) | qb(8) | kb(8) | ob(8).
// Transients xb/vt live inside d_out (16MB), dead before O-proj writes it.
// ---------------------------------------------------------------------------
extern "C" void kernel_launch(void* const* d_in, const int* in_sizes, int n_in,
                              void* d_out, int out_size, void* d_ws, size_t ws_size,
                              hipStream_t stream) {
    const float* x  = (const float*)d_in[0];
    const float* wq = (const float*)d_in[1];
    const float* bq = (const float*)d_in[2];
    const float* wk = (const float*)d_in[3];
    const float* bk = (const float*)d_in[4];
    const float* wv = (const float*)d_in[5];
    const float* bv = (const float*)d_in[6];
    const float* wo = (const float*)d_in[7];
    const float* bo = (const float*)d_in[8];
    float* out = (float*)d_out;

    const size_t E = (size_t)MROWS * DMODEL; // 4M elems
    u16* xb  = (u16*)d_out;      // bf16 x (dead after QKV GEMM)
    u16* vt  = xb + E;           // V^T (dead after attn)
    u16* wT  = (u16*)d_ws;       // wqT|wkT|wvT|woT, 4 x 1M elems
    u16* woT = wT + 3145728;
    u16* qb  = wT + 4194304;
    u16* kb  = qb + E;
    u16* ob  = kb + E;

    dim3 blk(256);
    prep_kernel<<<3072, blk, 0, stream>>>(x, xb, wq, wk, wv, wo, wT);

    // fused QKV: N=3072 (Bt rows = wqT|wkT|wvT), Q scale = log2e/8
    gemm_mfma<0><<<dim3(24, 32), blk, 0, stream>>>(
        xb, wT, bq, bk, bv, qb, kb, vt, nullptr, 0.18033688011112042f);

    dim3 agrid(16, BATCH * NHEADS); // paired q-tiles: uniform 33 iters/block
    attn_kernel<<<agrid, blk, 0, stream>>>(qb, kb, vt, ob);

    // O-proj: N=1024, fp32 out
    gemm_mfma<1><<<dim3(8, 32), blk, 0, stream>>>(
        ob, woT, bo, nullptr, nullptr, nullptr, nullptr, nullptr, out, 1.0f);
}

// Round 8
// 207.329 us; speedup vs baseline: 1.1340x; 1.0176x over previous
//
#include <hip/hip_runtime.h>
#include <math.h>

#define S_LEN 2048
#define BATCH 2
#define DMODEL 1024
#define NHEADS 16
#define MROWS 4096

typedef short bf8 __attribute__((ext_vector_type(8)));   // 8 x bf16 (4 VGPRs)
typedef float f32x4 __attribute__((ext_vector_type(4))); // MFMA accumulator
typedef unsigned short u16;

static __device__ inline u16 f2bf(float f) {
    union { float f; unsigned u; } v; v.f = f;
    unsigned r = v.u + 0x7fffu + ((v.u >> 16) & 1u); // RNE
    return (u16)(r >> 16);
}

// async global->LDS DMA, 16B per lane. LDS dest = (wave-uniform base) + lane*16.
static __device__ inline void load16(const void* g, void* l) {
    __builtin_amdgcn_global_load_lds(
        (const __attribute__((address_space(1))) unsigned int*)g,
        (__attribute__((address_space(3))) unsigned int*)l, 16, 0, 0);
}

// ---------------------------------------------------------------------------
// Fused prep: blocks [0,2048) convert x fp32->bf16 (8 elems/thread);
// blocks [2048,3072) transpose the 4 weights to Wt[n][k] bf16.
// ---------------------------------------------------------------------------
__global__ __launch_bounds__(256) void prep_kernel(
    const float* __restrict__ x, u16* __restrict__ xb,
    const float* __restrict__ W0, const float* __restrict__ W1,
    const float* __restrict__ W2, const float* __restrict__ W3,
    u16* __restrict__ wT) {
    const int bx = blockIdx.x, t = threadIdx.x;
    if (bx < 2048) {
        int i = bx * 256 + t;
        const float4* p = (const float4*)x + (size_t)i * 2;
        float4 a = p[0], b = p[1];
        u16 tmp[8] = {f2bf(a.x), f2bf(a.y), f2bf(a.z), f2bf(a.w),
                      f2bf(b.x), f2bf(b.y), f2bf(b.z), f2bf(b.w)};
        ((uint4*)xb)[i] = *(uint4*)tmp;
        return;
    }
    __shared__ u16 Ls[64][65];
    const int id = bx - 2048;
    const int z = id >> 8, rem = id & 255;
    const int n0 = (rem & 15) * 64, k0 = (rem >> 4) * 64;
    const float* W = z == 0 ? W0 : z == 1 ? W1 : z == 2 ? W2 : W3;
    u16* Wt = wT + (size_t)z * 1024 * 1024;
    const int r = t >> 2, c4 = (t & 3) * 16;
    const float* p = W + (size_t)(k0 + r) * 1024 + n0 + c4;
#pragma unroll
    for (int i = 0; i < 16; i += 4) {
        float4 v = *(const float4*)(p + i);
        Ls[r][c4 + i + 0] = f2bf(v.x);
        Ls[r][c4 + i + 1] = f2bf(v.y);
        Ls[r][c4 + i + 2] = f2bf(v.z);
        Ls[r][c4 + i + 3] = f2bf(v.w);
    }
    __syncthreads();
    u16 tmp[16];
#pragma unroll
    for (int i = 0; i < 16; i++) tmp[i] = Ls[c4 + i][r];
    uint4* q = (uint4*)(Wt + (size_t)(n0 + r) * 1024 + k0 + c4);
    q[0] = *(uint4*)tmp;
    q[1] = *(uint4*)(tmp + 8);
}

// ---------------------------------------------------------------------------
// m97-recipe GEMM with XOR-swizzled LDS banking.
// Swizzle: global-side permute (DMA slot l holds kgrp (l&3)^((l>>3)&3));
// reads use gslot = quad ^ ((l16>>1)&3)  -> 2-way banked b128 (free).
// 128x128 tile, BK=32, 4 waves x 64x64 quadrant.
// MODE 0: fused QKV (N=3072; sect 0->Q bf16*qscale, 1->K bf16, 2->V^T bf16)
// MODE 1: O-proj    (N=1024; fp32 row-major + bias)
// ---------------------------------------------------------------------------
template <int MODE>
__global__ __launch_bounds__(256) void gemm_mfma(
    const u16* __restrict__ A, const u16* __restrict__ Bt,
    const float* __restrict__ bqp, const float* __restrict__ bkp,
    const float* __restrict__ bvp,
    u16* __restrict__ qout, u16* __restrict__ kout, u16* __restrict__ vtout,
    float* __restrict__ fout, float qscale) {
    __shared__ __align__(16) u16 As[128 * 32];
    __shared__ __align__(16) u16 Bs[128 * 32];

    const int t = threadIdx.x, lane = t & 63, w = t >> 6;
    const int quad = lane >> 4, l16 = lane & 15;
    const int row0 = blockIdx.y * 128, col0 = blockIdx.x * 128;
    const int wr = (w >> 1) * 64, wc = (w & 1) * 64;
    const int K = DMODEL;

    const int srow = w * 32 + (lane >> 2);
    const int koff = (((lane & 3) ^ ((lane >> 3) & 3))) * 8; // swizzled kgrp
    const u16* ag = A + (size_t)(row0 + srow) * K + koff;
    const u16* bg = Bt + (size_t)(col0 + srow) * K + koff;
    u16* lA0 = As + (w * 32) * 32;
    u16* lA1 = As + (w * 32 + 16) * 32;
    u16* lB0 = Bs + (w * 32) * 32;
    u16* lB1 = Bs + (w * 32 + 16) * 32;
    const size_t r16 = (size_t)16 * K;

    const int swz = (l16 >> 1) & 3; // read-side swizzle

    f32x4 acc[4][4] = {};

    for (int k0 = 0; k0 < K; k0 += 32) {
        load16(ag + k0, lA0);
        load16(ag + r16 + k0, lA1);
        load16(bg + k0, lB0);
        load16(bg + r16 + k0, lB1);
        __syncthreads(); // drains vmcnt -> LDS valid
        bf8 af[4], bfr[4];
#pragma unroll
        for (int mi = 0; mi < 4; mi++)
            af[mi] = *(const bf8*)&As[(wr + mi * 16 + l16) * 32 + (quad ^ swz) * 8];
#pragma unroll
        for (int ni = 0; ni < 4; ni++)
            bfr[ni] = *(const bf8*)&Bs[(wc + ni * 16 + l16) * 32 + (quad ^ swz) * 8];
#pragma unroll
        for (int mi = 0; mi < 4; mi++)
#pragma unroll
            for (int ni = 0; ni < 4; ni++)
                acc[mi][ni] = __builtin_amdgcn_mfma_f32_16x16x32_bf16(
                    af[mi], bfr[ni], acc[mi][ni], 0, 0, 0);
        __syncthreads(); // all reads done before next iter's DMA overwrites
    }

    const int sect = (col0 + wc) >> 10; // uniform per wave (64-aligned spans)
#pragma unroll
    for (int mi = 0; mi < 4; mi++) {
        const int r = row0 + wr + mi * 16 + quad * 4;
#pragma unroll
        for (int ni = 0; ni < 4; ni++) {
            const int c = col0 + wc + ni * 16 + l16;
            if (MODE == 1) {
                float bvv = bqp[c];
#pragma unroll
                for (int reg = 0; reg < 4; reg++)
                    fout[(size_t)(r + reg) * 1024 + c] = acc[mi][ni][reg] + bvv;
            } else {
                const int cl = c & 1023;
                const float* bp = sect == 0 ? bqp : sect == 1 ? bkp : bvp;
                float bvv = bp[cl];
                if (sect == 0) {
#pragma unroll
                    for (int reg = 0; reg < 4; reg++)
                        qout[(size_t)(r + reg) * 1024 + cl] =
                            f2bf((acc[mi][ni][reg] + bvv) * qscale);
                } else if (sect == 1) {
#pragma unroll
                    for (int reg = 0; reg < 4; reg++)
                        kout[(size_t)(r + reg) * 1024 + cl] =
                            f2bf(acc[mi][ni][reg] + bvv);
                } else { // V^T: Vt[(r>>11)*1024 + cl][r&2047 .. +3]
                    u16 t4[4];
#pragma unroll
                    for (int reg = 0; reg < 4; reg++)
                        t4[reg] = f2bf(acc[mi][ni][reg] + bvv);
                    *(uint2*)(vtout + ((size_t)(r >> 11) * 1024 + cl) * S_LEN +
                              (r & 2047)) = *(uint2*)t4;
                }
            }
        }
    }
}

// ---------------------------------------------------------------------------
// Flash attention, causal, no-max softmax via exp2 (log2e*scale folded in Q).
// Paired q-tiles (pi, 31-pi) -> uniform 33 k-iters/block. 4 waves x 16 q.
// XOR-swizzled Ks/Vs/Ps LDS: all b128 fragment reads 2-way banked.
// ---------------------------------------------------------------------------
__global__ __launch_bounds__(256) void attn_kernel(const u16* __restrict__ Qg,
                                                   const u16* __restrict__ Kg,
                                                   const u16* __restrict__ Vt,
                                                   u16* __restrict__ Og) {
    __shared__ __align__(16) u16 Ks[2][64][32];  // [d-half][key][kgrp swz]
    __shared__ __align__(16) u16 Vs[2][64][32];  // [key-half][d][kgrp swz]
    __shared__ __align__(16) u16 Ps[4][16][64];  // [wave][q][key, q-swz]

    const int t = threadIdx.x, lane = t & 63, w = t >> 6;
    const int quad = lane >> 4, l16 = lane & 15;
    const int pi = blockIdx.x;
    const int bh = blockIdx.y, b = bh >> 4, h = bh & 15;
    const size_t base = (size_t)b * S_LEN * DMODEL + h * 64;
    const size_t vbase = ((size_t)b * 1024 + h * 64) * S_LEN;
    const int sr = t >> 2, sc = (t & 3) * 16;
    const int pl = sc >> 5;                 // plane
    const int g0 = (sc >> 3) & 3;           // first kgrp in plane (0 or 2)
    const int ss = (sr >> 1) & 3;           // staging swizzle
    const int swz = (l16 >> 1) & 3;         // K/V read swizzle
    const int pswz = l16 & 7;               // P read swizzle (q = l16)

    const u16* kp = Kg + base + (size_t)sr * DMODEL + sc;
    const u16* vp = Vt + vbase + (size_t)sr * S_LEN + sc;
    uint4 k0r = *(const uint4*)kp, k1r = *(const uint4*)(kp + 8);
    uint4 v0r = *(const uint4*)vp, v1r = *(const uint4*)(vp + 8);

#pragma unroll
    for (int seg = 0; seg < 2; seg++) {
        const int qt = seg == 0 ? pi : 31 - pi;
        const int niter = qt + 1;
        const int q0 = qt * 64;

        bf8 aq[2];
#pragma unroll
        for (int c = 0; c < 2; c++)
            aq[c] = *(const bf8*)(Qg + base +
                (size_t)(q0 + w * 16 + l16) * DMODEL + c * 32 + quad * 8);

        float lsum[4] = {};
        f32x4 o_acc[4] = {};

        for (int kt = 0; kt < niter; kt++) {
            __syncthreads();
            *(uint4*)&Ks[pl][sr][(g0 ^ ss) * 8] = k0r;
            *(uint4*)&Ks[pl][sr][((g0 + 1) ^ ss) * 8] = k1r;
            *(uint4*)&Vs[pl][sr][(g0 ^ ss) * 8] = v0r;
            *(uint4*)&Vs[pl][sr][((g0 + 1) ^ ss) * 8] = v1r;
            __syncthreads();
            // prefetch next K/V tile (next kt, or tile 0 of segment B)
            if (!(seg == 1 && kt + 1 == niter)) {
                int nt = (kt + 1 < niter) ? kt + 1 : 0;
                size_t ok = (size_t)nt * 64 * DMODEL;
                int ov = nt * 64;
                k0r = *(const uint4*)(kp + ok); k1r = *(const uint4*)(kp + ok + 8);
                v0r = *(const uint4*)(vp + ov); v1r = *(const uint4*)(vp + ov + 8);
            }

            // S = Q K^T: 16q x 64key per wave
            f32x4 scv[4] = {};
#pragma unroll
            for (int c = 0; c < 2; c++)
#pragma unroll
                for (int ns = 0; ns < 4; ns++) {
                    bf8 bk = *(const bf8*)&Ks[c][ns * 16 + l16][(quad ^ swz) * 8];
                    scv[ns] = __builtin_amdgcn_mfma_f32_16x16x32_bf16(
                        aq[c], bk, scv[ns], 0, 0, 0);
                }

            // exp2 (scale*log2e folded into Q); mask only the diagonal tile
            const bool diag = (kt == qt);
            const int myq = w * 16 + quad * 4;
#pragma unroll
            for (int ns = 0; ns < 4; ns++) {
                int key = ns * 16 + l16;
#pragma unroll
                for (int r = 0; r < 4; r++) {
                    float p = (diag && key > myq + r)
                                  ? 0.f
                                  : __builtin_amdgcn_exp2f(scv[ns][r]);
                    lsum[r] += p;
                    const int q = quad * 4 + r;
                    const int g = ns * 2 + (l16 >> 3);
                    Ps[w][q][((g ^ (q & 7)) * 8) + (l16 & 7)] =
                        (u16)(__float_as_uint(p) >> 16); // trunc pack
                }
            }
            asm volatile("s_waitcnt lgkmcnt(0)" ::: "memory"); // wave-private W->R

            // O += P @ V
#pragma unroll
            for (int kc = 0; kc < 2; kc++) {
                bf8 apv = *(const bf8*)&Ps[w][l16][((kc * 4 + quad) ^ pswz) * 8];
#pragma unroll
                for (int ds = 0; ds < 4; ds++) {
                    bf8 bvv = *(const bf8*)&Vs[kc][ds * 16 + l16][(quad ^ swz) * 8];
                    o_acc[ds] = __builtin_amdgcn_mfma_f32_16x16x32_bf16(
                        apv, bvv, o_acc[ds], 0, 0, 0);
                }
            }
        }

        // epilogue: reduce l across the 16 key-lanes, normalize, store
#pragma unroll
        for (int r = 0; r < 4; r++) {
            float l = lsum[r];
#pragma unroll
            for (int off = 8; off >= 1; off >>= 1) l += __shfl_xor(l, off, 64);
            float inv = 1.f / l;
            int qq = q0 + w * 16 + quad * 4 + r;
#pragma unroll
            for (int ds = 0; ds < 4; ds++)
                Og[base + (size_t)qq * DMODEL + ds * 16 + l16] =
                    f2bf(o_acc[ds][r] * inv);
        }
    }
}

// ---------------------------------------------------------------------------
// Workspace: d_ws 32MB = wT(8) | qb(8) | kb(8) | ob(8).
// Transients xb/vt live inside d_out (16MB), dead before O-proj writes it.
// ---------------------------------------------------------------------------
extern "C" void kernel_launch(void* const* d_in, const int* in_sizes, int n_in,
                              void* d_out, int out_size, void* d_ws, size_t ws_size,
                              hipStream_t stream) {
    const float* x  = (const float*)d_in[0];
    const float* wq = (const float*)d_in[1];
    const float* bq = (const float*)d_in[2];
    const float* wk = (const float*)d_in[3];
    const float* bk = (const float*)d_in[4];
    const float* wv = (const float*)d_in[5];
    const float* bv = (const float*)d_in[6];
    const float* wo = (const float*)d_in[7];
    const float* bo = (const float*)d_in[8];
    float* out = (float*)d_out;

    const size_t E = (size_t)MROWS * DMODEL; // 4M elems
    u16* xb  = (u16*)d_out;      // bf16 x (dead after QKV GEMM)
    u16* vt  = xb + E;           // V^T (dead after attn)
    u16* wT  = (u16*)d_ws;       // wqT|wkT|wvT|woT, 4 x 1M elems
    u16* woT = wT + 3145728;
    u16* qb  = wT + 4194304;
    u16* kb  = qb + E;
    u16* ob  = kb + E;

    dim3 blk(256);
    prep_kernel<<<3072, blk, 0, stream>>>(x, xb, wq, wk, wv, wo, wT);

    // fused QKV: N=3072 (Bt rows = wqT|wkT|wvT), Q scale = log2e/8
    gemm_mfma<0><<<dim3(24, 32), blk, 0, stream>>>(
        xb, wT, bq, bk, bv, qb, kb, vt, nullptr, 0.18033688011112042f);

    dim3 agrid(16, BATCH * NHEADS); // paired q-tiles: uniform 33 iters/block
    attn_kernel<<<agrid, blk, 0, stream>>>(qb, kb, vt, ob);

    // O-proj: N=1024, fp32 out
    gemm_mfma<1><<<dim3(8, 32), blk, 0, stream>>>(
        ob, woT, bo, nullptr, nullptr, nullptr, nullptr, nullptr, out, 1.0f);
}

// Round 9
// 207.021 us; speedup vs baseline: 1.1357x; 1.0015x over previous
//
#include <hip/hip_runtime.h>
#include <math.h>

#define S_LEN 2048
#define BATCH 2
#define DMODEL 1024
#define NHEADS 16
#define MROWS 4096

typedef short bf8 __attribute__((ext_vector_type(8)));   // 8 x bf16 (4 VGPRs)
typedef float f32x4 __attribute__((ext_vector_type(4))); // MFMA accumulator
typedef unsigned short u16;

static __device__ inline u16 f2bf(float f) {
    union { float f; unsigned u; } v; v.f = f;
    unsigned r = v.u + 0x7fffu + ((v.u >> 16) & 1u); // RNE
    return (u16)(r >> 16);
}

// async global->LDS DMA, 16B per lane. LDS dest = (wave-uniform base) + lane*16.
static __device__ inline void load16(const void* g, void* l) {
    __builtin_amdgcn_global_load_lds(
        (const __attribute__((address_space(1))) unsigned int*)g,
        (__attribute__((address_space(3))) unsigned int*)l, 16, 0, 0);
}

// ---------------------------------------------------------------------------
// Fused prep: blocks [0,2048) convert x fp32->bf16; [2048,3072) transpose
// the 4 weights to Wt[n][k] bf16.
// ---------------------------------------------------------------------------
__global__ __launch_bounds__(256) void prep_kernel(
    const float* __restrict__ x, u16* __restrict__ xb,
    const float* __restrict__ W0, const float* __restrict__ W1,
    const float* __restrict__ W2, const float* __restrict__ W3,
    u16* __restrict__ wT) {
    const int bx = blockIdx.x, t = threadIdx.x;
    if (bx < 2048) {
        int i = bx * 256 + t;
        const float4* p = (const float4*)x + (size_t)i * 2;
        float4 a = p[0], b = p[1];
        u16 tmp[8] = {f2bf(a.x), f2bf(a.y), f2bf(a.z), f2bf(a.w),
                      f2bf(b.x), f2bf(b.y), f2bf(b.z), f2bf(b.w)};
        ((uint4*)xb)[i] = *(uint4*)tmp;
        return;
    }
    __shared__ u16 Ls[64][65];
    const int id = bx - 2048;
    const int z = id >> 8, rem = id & 255;
    const int n0 = (rem & 15) * 64, k0 = (rem >> 4) * 64;
    const float* W = z == 0 ? W0 : z == 1 ? W1 : z == 2 ? W2 : W3;
    u16* Wt = wT + (size_t)z * 1024 * 1024;
    const int r = t >> 2, c4 = (t & 3) * 16;
    const float* p = W + (size_t)(k0 + r) * 1024 + n0 + c4;
#pragma unroll
    for (int i = 0; i < 16; i += 4) {
        float4 v = *(const float4*)(p + i);
        Ls[r][c4 + i + 0] = f2bf(v.x);
        Ls[r][c4 + i + 1] = f2bf(v.y);
        Ls[r][c4 + i + 2] = f2bf(v.z);
        Ls[r][c4 + i + 3] = f2bf(v.w);
    }
    __syncthreads();
    u16 tmp[16];
#pragma unroll
    for (int i = 0; i < 16; i++) tmp[i] = Ls[c4 + i][r];
    uint4* q = (uint4*)(Wt + (size_t)(n0 + r) * 1024 + k0 + c4);
    q[0] = *(uint4*)tmp;
    q[1] = *(uint4*)(tmp + 8);
}

// ---------------------------------------------------------------------------
// Swapped-operand MFMA GEMM: D[feature][xrow] = W-frag(A) x x-frag(B).
// acc regs = 4 consecutive features -> packed epilogue stores.
// XOR-swizzled LDS (R8-verified, 0 conflicts).
// MODE 0: QKV. tile 128 xrows x 128 features, grid (24,32).
//   sect 0 -> Q bf16*qscale (uint2), 1 -> K bf16 (uint2), 2 -> V^T (u16 x4)
// MODE 1: O-proj. tile 64 xrows x 128 features, grid (8,64). fp32 float4 out.
// ---------------------------------------------------------------------------
template <int MODE>
__global__ __launch_bounds__(256) void gemm_mfma(
    const u16* __restrict__ A, const u16* __restrict__ Bt,
    const float* __restrict__ bqp, const float* __restrict__ bkp,
    const float* __restrict__ bvp,
    u16* __restrict__ qout, u16* __restrict__ kout, u16* __restrict__ vtout,
    float* __restrict__ fout, float qscale) {
    constexpr int TM = (MODE == 1) ? 64 : 128; // xrows per block
    constexpr int MI = (MODE == 1) ? 2 : 4;    // feature groups per wave
    __shared__ __align__(16) u16 As[TM * 32];  // x rows
    __shared__ __align__(16) u16 Bs[128 * 32]; // W rows (features)

    const int t = threadIdx.x, lane = t & 63, w = t >> 6;
    const int quad = lane >> 4, l16 = lane & 15;
    const int row0 = blockIdx.y * TM, col0 = blockIdx.x * 128;
    const int fq = (MODE == 1) ? w * 32 : (w & 1) * 64;
    const int xq = (MODE == 1) ? 0 : (w >> 1) * 64;
    const int K = DMODEL;

    const int koff = (((lane & 3) ^ ((lane >> 3) & 3))) * 8; // swizzled kgrp
    const int srowA = (MODE == 1) ? (w * 16 + (lane >> 2)) : (w * 32 + (lane >> 2));
    const int srowB = w * 32 + (lane >> 2);
    const u16* ag = A + (size_t)(row0 + srowA) * K + koff;
    const u16* bg = Bt + (size_t)(col0 + srowB) * K + koff;
    u16* lA0 = As + ((MODE == 1) ? (w * 16) : (w * 32)) * 32;
    u16* lA1 = As + (w * 32 + 16) * 32; // MODE0 only
    u16* lB0 = Bs + (w * 32) * 32;
    u16* lB1 = Bs + (w * 32 + 16) * 32;
    const size_t r16 = (size_t)16 * K;

    const int swz = (l16 >> 1) & 3;

    f32x4 acc[MI][4] = {};

    for (int k0 = 0; k0 < K; k0 += 32) {
        load16(ag + k0, lA0);
        if (MODE == 0) load16(ag + r16 + k0, lA1);
        load16(bg + k0, lB0);
        load16(bg + r16 + k0, lB1);
        __syncthreads(); // drains vmcnt -> LDS valid
        bf8 xf[4], wf[MI];
#pragma unroll
        for (int ni = 0; ni < 4; ni++)
            xf[ni] = *(const bf8*)&As[(xq + ni * 16 + l16) * 32 + (quad ^ swz) * 8];
#pragma unroll
        for (int mi = 0; mi < MI; mi++)
            wf[mi] = *(const bf8*)&Bs[(fq + mi * 16 + l16) * 32 + (quad ^ swz) * 8];
#pragma unroll
        for (int mi = 0; mi < MI; mi++)
#pragma unroll
            for (int ni = 0; ni < 4; ni++)
                acc[mi][ni] = __builtin_amdgcn_mfma_f32_16x16x32_bf16(
                    wf[mi], xf[ni], acc[mi][ni], 0, 0, 0);
        __syncthreads(); // reads done before next DMA overwrites
    }

    const int sect = (col0 + fq) >> 10; // uniform per wave
#pragma unroll
    for (int mi = 0; mi < MI; mi++) {
        const int featb = col0 + fq + mi * 16 + quad * 4;
        float b4[4];
#pragma unroll
        for (int reg = 0; reg < 4; reg++)
            b4[reg] = (MODE == 1 ? bqp : (sect == 0 ? bqp : sect == 1 ? bkp : bvp))
                          [(featb + reg) & 1023];
#pragma unroll
        for (int ni = 0; ni < 4; ni++) {
            const int xrow = row0 + xq + ni * 16 + l16;
            if (MODE == 1) {
                float4 o;
                o.x = acc[mi][ni][0] + b4[0];
                o.y = acc[mi][ni][1] + b4[1];
                o.z = acc[mi][ni][2] + b4[2];
                o.w = acc[mi][ni][3] + b4[3];
                *(float4*)(fout + (size_t)xrow * 1024 + featb) = o;
            } else {
                const int cf = featb & 1023;
                if (sect == 0) {
                    u16 t4[4];
#pragma unroll
                    for (int reg = 0; reg < 4; reg++)
                        t4[reg] = f2bf((acc[mi][ni][reg] + b4[reg]) * qscale);
                    *(uint2*)(qout + (size_t)xrow * 1024 + cf) = *(uint2*)t4;
                } else if (sect == 1) {
                    u16 t4[4];
#pragma unroll
                    for (int reg = 0; reg < 4; reg++)
                        t4[reg] = f2bf(acc[mi][ni][reg] + b4[reg]);
                    *(uint2*)(kout + (size_t)xrow * 1024 + cf) = *(uint2*)t4;
                } else { // V^T: Vt[(xrow>>11)*1024 + f][xrow&2047]
#pragma unroll
                    for (int reg = 0; reg < 4; reg++)
                        vtout[((size_t)(xrow >> 11) * 1024 + cf + reg) * S_LEN +
                              (xrow & 2047)] = f2bf(acc[mi][ni][reg] + b4[reg]);
                }
            }
        }
    }
}

// ---------------------------------------------------------------------------
// Flash attention, causal, no-max exp2 softmax. Paired q-tiles (pi,31-pi),
// 128-key double-tiles -> uniformly 17 double-iters/block (2 barriers each).
// XOR-swizzled Ks/Vs/Ps. Phantom half-tiles auto-zeroed by global causal mask.
// ---------------------------------------------------------------------------
__global__ __launch_bounds__(256) void attn_kernel(const u16* __restrict__ Qg,
                                                   const u16* __restrict__ Kg,
                                                   const u16* __restrict__ Vt,
                                                   u16* __restrict__ Og) {
    __shared__ __align__(16) u16 Ks[2][128][32]; // [d-half][key][kslot]
    __shared__ __align__(16) u16 Vs[4][64][32];  // [key-qtr][d][kslot]
    __shared__ __align__(16) u16 Ps[4][16][128]; // [wave][q][key slots]

    const int t = threadIdx.x, lane = t & 63, w = t >> 6;
    const int quad = lane >> 4, l16 = lane & 15;
    const int pi = blockIdx.x;
    const int bh = blockIdx.y, b = bh >> 4, h = bh & 15;
    const size_t base = (size_t)b * S_LEN * DMODEL + h * 64;
    const size_t vbase = ((size_t)b * 1024 + h * 64) * S_LEN;
    const int sr = t >> 2, sc = (t & 3) * 16;
    const int pl = sc >> 5;                // d-half / key-qtr low bit
    const int g0 = (sc >> 3) & 3;          // first kgrp slot
    const int ss = (sr >> 1) & 3;          // staging swizzle (row%16 based)
    const int swz = (l16 >> 1) & 3;        // frag-read swizzle

    const u16* kp = Kg + base + (size_t)sr * DMODEL + sc;
    const u16* vp = Vt + vbase + (size_t)sr * S_LEN + sc;
    const size_t kr64 = (size_t)64 * DMODEL;

    // prefetch double-tile 0 (keys 0..127)
    uint4 k0r = *(const uint4*)kp, k1r = *(const uint4*)(kp + 8);
    uint4 k2r = *(const uint4*)(kp + kr64), k3r = *(const uint4*)(kp + kr64 + 8);
    uint4 v0r = *(const uint4*)vp, v1r = *(const uint4*)(vp + 8);
    uint4 v2r = *(const uint4*)(vp + 64), v3r = *(const uint4*)(vp + 72);

#pragma unroll
    for (int seg = 0; seg < 2; seg++) {
        const int qt = seg == 0 ? pi : 31 - pi;
        const int niter = qt + 1;          // 64-key tiles
        const int nd = (niter + 1) >> 1;   // 128-key double-tiles
        const int q0 = qt * 64;

        bf8 aq[2];
#pragma unroll
        for (int c = 0; c < 2; c++)
            aq[c] = *(const bf8*)(Qg + base +
                (size_t)(q0 + w * 16 + l16) * DMODEL + c * 32 + quad * 8);

        float lsum[4] = {};
        f32x4 o_acc[4] = {};

        for (int j = 0; j < nd; j++) {
            __syncthreads();
            *(uint4*)&Ks[pl][sr][(g0 ^ ss) * 8] = k0r;
            *(uint4*)&Ks[pl][sr][((g0 + 1) ^ ss) * 8] = k1r;
            *(uint4*)&Ks[pl][sr + 64][(g0 ^ ss) * 8] = k2r;
            *(uint4*)&Ks[pl][sr + 64][((g0 + 1) ^ ss) * 8] = k3r;
            *(uint4*)&Vs[pl][sr][(g0 ^ ss) * 8] = v0r;
            *(uint4*)&Vs[pl][sr][((g0 + 1) ^ ss) * 8] = v1r;
            *(uint4*)&Vs[2 + pl][sr][(g0 ^ ss) * 8] = v2r;
            *(uint4*)&Vs[2 + pl][sr][((g0 + 1) ^ ss) * 8] = v3r;
            __syncthreads();

            // prefetch next double-tile (or tile 0 for segment B)
            if (j + 1 < nd || seg == 0) {
                size_t ok = (j + 1 < nd) ? (size_t)(j + 1) * 128 * DMODEL : 0;
                int ov = (j + 1 < nd) ? (j + 1) * 128 : 0;
                k0r = *(const uint4*)(kp + ok);
                k1r = *(const uint4*)(kp + ok + 8);
                k2r = *(const uint4*)(kp + ok + kr64);
                k3r = *(const uint4*)(kp + ok + kr64 + 8);
                v0r = *(const uint4*)(vp + ov);
                v1r = *(const uint4*)(vp + ov + 8);
                v2r = *(const uint4*)(vp + ov + 64);
                v3r = *(const uint4*)(vp + ov + 72);
            }

            // S = Q K^T : 16q x 128key per wave
            f32x4 scv[8] = {};
#pragma unroll
            for (int c = 0; c < 2; c++)
#pragma unroll
                for (int ns = 0; ns < 8; ns++) {
                    bf8 bk = *(const bf8*)&Ks[c][ns * 16 + l16][(quad ^ swz) * 8];
                    scv[ns] = __builtin_amdgcn_mfma_f32_16x16x32_bf16(
                        aq[c], bk, scv[ns], 0, 0, 0);
                }

            // exp2; global causal mask on the last double-tile covers both the
            // diagonal tile and any phantom (odd-count) half-tile.
            const bool lastd = (j == nd - 1);
            const int qbase = q0 + w * 16 + quad * 4;
#pragma unroll
            for (int ns = 0; ns < 8; ns++) {
                const int key_g = j * 128 + ns * 16 + l16;
                const int g = ns * 2 + (l16 >> 3);
#pragma unroll
                for (int r = 0; r < 4; r++) {
                    float p = (lastd && key_g > qbase + r)
                                  ? 0.f
                                  : __builtin_amdgcn_exp2f(scv[ns][r]);
                    lsum[r] += p;
                    const int q = quad * 4 + r;
                    Ps[w][q][(g ^ (q & 7)) * 8 + (l16 & 7)] =
                        (u16)(__float_as_uint(p) >> 16); // trunc pack
                }
            }
            asm volatile("s_waitcnt lgkmcnt(0)" ::: "memory"); // wave-private W->R

            // O += P @ V over 128 keys
#pragma unroll
            for (int kk = 0; kk < 4; kk++) {
                bf8 apv = *(const bf8*)&Ps[w][l16][((kk * 4 + quad) ^ (l16 & 7)) * 8];
#pragma unroll
                for (int ds = 0; ds < 4; ds++) {
                    bf8 bvv = *(const bf8*)&Vs[kk][ds * 16 + l16][(quad ^ swz) * 8];
                    o_acc[ds] = __builtin_amdgcn_mfma_f32_16x16x32_bf16(
                        apv, bvv, o_acc[ds], 0, 0, 0);
                }
            }
        }

        // epilogue: reduce l across the 16 key-lanes, normalize, store
#pragma unroll
        for (int r = 0; r < 4; r++) {
            float l = lsum[r];
#pragma unroll
            for (int off = 8; off >= 1; off >>= 1) l += __shfl_xor(l, off, 64);
            float inv = 1.f / l;
            int qq = q0 + w * 16 + quad * 4 + r;
#pragma unroll
            for (int ds = 0; ds < 4; ds++)
                Og[base + (size_t)qq * DMODEL + ds * 16 + l16] =
                    f2bf(o_acc[ds][r] * inv);
        }
    }
}

// ---------------------------------------------------------------------------
// Workspace: d_ws 32MB = wT(8) | qb(8) | kb(8) | ob(8).
// Transients xb/vt live inside d_out (16MB), dead before O-proj writes it.
// ---------------------------------------------------------------------------
extern "C" void kernel_launch(void* const* d_in, const int* in_sizes, int n_in,
                              void* d_out, int out_size, void* d_ws, size_t ws_size,
                              hipStream_t stream) {
    const float* x  = (const float*)d_in[0];
    const float* wq = (const float*)d_in[1];
    const float* bq = (const float*)d_in[2];
    const float* wk = (const float*)d_in[3];
    const float* bk = (const float*)d_in[4];
    const float* wv = (const float*)d_in[5];
    const float* bv = (const float*)d_in[6];
    const float* wo = (const float*)d_in[7];
    const float* bo = (const float*)d_in[8];
    float* out = (float*)d_out;

    const size_t E = (size_t)MROWS * DMODEL; // 4M elems
    u16* xb  = (u16*)d_out;      // bf16 x (dead after QKV GEMM)
    u16* vt  = xb + E;           // V^T (dead after attn)
    u16* wT  = (u16*)d_ws;       // wqT|wkT|wvT|woT
    u16* woT = wT + 3145728;
    u16* qb  = wT + 4194304;
    u16* kb  = qb + E;
    u16* ob  = kb + E;

    dim3 blk(256);
    prep_kernel<<<3072, blk, 0, stream>>>(x, xb, wq, wk, wv, wo, wT);

    // fused QKV: N=3072, Q scale = log2e/8
    gemm_mfma<0><<<dim3(24, 32), blk, 0, stream>>>(
        xb, wT, bq, bk, bv, qb, kb, vt, nullptr, 0.18033688011112042f);

    dim3 agrid(16, BATCH * NHEADS); // paired q-tiles, 17 double-iters each
    attn_kernel<<<agrid, blk, 0, stream>>>(qb, kb, vt, ob);

    // O-proj: 64x128 tiles, 512 blocks, fp32 float4 stores
    gemm_mfma<1><<<dim3(8, 64), blk, 0, stream>>>(
        ob, woT, bo, nullptr, nullptr, nullptr, nullptr, nullptr, out, 1.0f);
}

// Round 10
// 197.382 us; speedup vs baseline: 1.1912x; 1.0488x over previous
//
#include <hip/hip_runtime.h>
#include <math.h>

#define S_LEN 2048
#define BATCH 2
#define DMODEL 1024
#define NHEADS 16
#define MROWS 4096

typedef short bf8 __attribute__((ext_vector_type(8)));   // 8 x bf16
typedef short bf4 __attribute__((ext_vector_type(4)));   // 4 x bf16
typedef float f32x4 __attribute__((ext_vector_type(4))); // MFMA accumulator
typedef unsigned short u16;

static __device__ inline u16 f2bf(float f) {
    union { float f; unsigned u; } v; v.f = f;
    unsigned r = v.u + 0x7fffu + ((v.u >> 16) & 1u); // RNE
    return (u16)(r >> 16);
}

// async global->LDS DMA, 16B per lane. LDS dest = (wave-uniform base) + lane*16.
static __device__ inline void load16(const void* g, void* l) {
    __builtin_amdgcn_global_load_lds(
        (const __attribute__((address_space(1))) unsigned int*)g,
        (__attribute__((address_space(3))) unsigned int*)l, 16, 0, 0);
}

// ---------------------------------------------------------------------------
// Fused prep: blocks [0,2048) convert x fp32->bf16; [2048,3072) transpose
// the 4 weights to Wt[n][k] bf16.
// ---------------------------------------------------------------------------
__global__ __launch_bounds__(256) void prep_kernel(
    const float* __restrict__ x, u16* __restrict__ xb,
    const float* __restrict__ W0, const float* __restrict__ W1,
    const float* __restrict__ W2, const float* __restrict__ W3,
    u16* __restrict__ wT) {
    const int bx = blockIdx.x, t = threadIdx.x;
    if (bx < 2048) {
        int i = bx * 256 + t;
        const float4* p = (const float4*)x + (size_t)i * 2;
        float4 a = p[0], b = p[1];
        u16 tmp[8] = {f2bf(a.x), f2bf(a.y), f2bf(a.z), f2bf(a.w),
                      f2bf(b.x), f2bf(b.y), f2bf(b.z), f2bf(b.w)};
        ((uint4*)xb)[i] = *(uint4*)tmp;
        return;
    }
    __shared__ u16 Ls[64][65];
    const int id = bx - 2048;
    const int z = id >> 8, rem = id & 255;
    const int n0 = (rem & 15) * 64, k0 = (rem >> 4) * 64;
    const float* W = z == 0 ? W0 : z == 1 ? W1 : z == 2 ? W2 : W3;
    u16* Wt = wT + (size_t)z * 1024 * 1024;
    const int r = t >> 2, c4 = (t & 3) * 16;
    const float* p = W + (size_t)(k0 + r) * 1024 + n0 + c4;
#pragma unroll
    for (int i = 0; i < 16; i += 4) {
        float4 v = *(const float4*)(p + i);
        Ls[r][c4 + i + 0] = f2bf(v.x);
        Ls[r][c4 + i + 1] = f2bf(v.y);
        Ls[r][c4 + i + 2] = f2bf(v.z);
        Ls[r][c4 + i + 3] = f2bf(v.w);
    }
    __syncthreads();
    u16 tmp[16];
#pragma unroll
    for (int i = 0; i < 16; i++) tmp[i] = Ls[c4 + i][r];
    uint4* q = (uint4*)(Wt + (size_t)(n0 + r) * 1024 + k0 + c4);
    q[0] = *(uint4*)tmp;
    q[1] = *(uint4*)(tmp + 8);
}

// ---------------------------------------------------------------------------
// Swapped-operand MFMA GEMM, BK=64 (16 barrier-pairs, 32 MFMA each).
// LDS rows are 64 elems (128B); XOR swizzle slot=(kc*4+quad)^(l16&7) -> 2-way.
// MODE 0: QKV. 128 xrows x 128 features, grid (24,32).
// MODE 1: O-proj. 64 xrows x 128 features, grid (8,64). fp32 float4 out.
// ---------------------------------------------------------------------------
template <int MODE>
__global__ __launch_bounds__(256) void gemm_mfma(
    const u16* __restrict__ A, const u16* __restrict__ Bt,
    const float* __restrict__ bqp, const float* __restrict__ bkp,
    const float* __restrict__ bvp,
    u16* __restrict__ qout, u16* __restrict__ kout, u16* __restrict__ vtout,
    float* __restrict__ fout, float qscale) {
    constexpr int TM = (MODE == 1) ? 64 : 128; // xrows per block
    constexpr int MI = (MODE == 1) ? 2 : 4;    // feature groups per wave
    constexpr int ADMA = (MODE == 1) ? 2 : 4;  // A-DMAs per wave per iter
    __shared__ __align__(16) u16 As[TM * 64];  // x rows
    __shared__ __align__(16) u16 Bs[128 * 64]; // W rows (features)

    const int t = threadIdx.x, lane = t & 63, w = t >> 6;
    const int quad = lane >> 4, l16 = lane & 15;
    const int row0 = blockIdx.y * TM, col0 = blockIdx.x * 128;
    const int fq = (MODE == 1) ? w * 32 : (w & 1) * 64;
    const int xq = (MODE == 1) ? 0 : (w >> 1) * 64;
    const int K = DMODEL;

    const int lrow = lane >> 3;                        // 0..7
    const int koff = ((lane & 7) ^ lrow) * 8;          // swizzled k-group
    const int abase = (MODE == 1) ? w * 16 : w * 32;
    const u16* ag = A + (size_t)(row0 + abase + lrow) * K + koff;
    const u16* bg = Bt + (size_t)(col0 + w * 32 + lrow) * K + koff;
    u16* lA = As + abase * 64;
    u16* lB = Bs + (w * 32) * 64;
    const int swz = l16 & 7;

    f32x4 acc[MI][4] = {};

    for (int k0 = 0; k0 < K; k0 += 64) {
#pragma unroll
        for (int d = 0; d < ADMA; d++)
            load16(ag + (size_t)d * 8 * K + k0, lA + d * 512);
#pragma unroll
        for (int d = 0; d < 4; d++)
            load16(bg + (size_t)d * 8 * K + k0, lB + d * 512);
        __syncthreads(); // drains vmcnt -> LDS valid
#pragma unroll
        for (int kc = 0; kc < 2; kc++) {
            bf8 xf[4], wf[MI];
#pragma unroll
            for (int ni = 0; ni < 4; ni++)
                xf[ni] = *(const bf8*)&As[(xq + ni * 16 + l16) * 64 +
                                          ((kc * 4 + quad) ^ swz) * 8];
#pragma unroll
            for (int mi = 0; mi < MI; mi++)
                wf[mi] = *(const bf8*)&Bs[(fq + mi * 16 + l16) * 64 +
                                          ((kc * 4 + quad) ^ swz) * 8];
#pragma unroll
            for (int mi = 0; mi < MI; mi++)
#pragma unroll
                for (int ni = 0; ni < 4; ni++)
                    acc[mi][ni] = __builtin_amdgcn_mfma_f32_16x16x32_bf16(
                        wf[mi], xf[ni], acc[mi][ni], 0, 0, 0);
        }
        __syncthreads(); // reads done before next DMA overwrites
    }

    const int sect = (col0 + fq) >> 10; // uniform per wave
#pragma unroll
    for (int mi = 0; mi < MI; mi++) {
        const int featb = col0 + fq + mi * 16 + quad * 4;
        float b4[4];
#pragma unroll
        for (int reg = 0; reg < 4; reg++)
            b4[reg] = (MODE == 1 ? bqp : (sect == 0 ? bqp : sect == 1 ? bkp : bvp))
                          [(featb + reg) & 1023];
#pragma unroll
        for (int ni = 0; ni < 4; ni++) {
            const int xrow = row0 + xq + ni * 16 + l16;
            if (MODE == 1) {
                float4 o;
                o.x = acc[mi][ni][0] + b4[0];
                o.y = acc[mi][ni][1] + b4[1];
                o.z = acc[mi][ni][2] + b4[2];
                o.w = acc[mi][ni][3] + b4[3];
                *(float4*)(fout + (size_t)xrow * 1024 + featb) = o;
            } else {
                const int cf = featb & 1023;
                if (sect == 0) {
                    u16 t4[4];
#pragma unroll
                    for (int reg = 0; reg < 4; reg++)
                        t4[reg] = f2bf((acc[mi][ni][reg] + b4[reg]) * qscale);
                    *(uint2*)(qout + (size_t)xrow * 1024 + cf) = *(uint2*)t4;
                } else if (sect == 1) {
                    u16 t4[4];
#pragma unroll
                    for (int reg = 0; reg < 4; reg++)
                        t4[reg] = f2bf(acc[mi][ni][reg] + b4[reg]);
                    *(uint2*)(kout + (size_t)xrow * 1024 + cf) = *(uint2*)t4;
                } else { // V^T: Vt[(xrow>>11)*1024 + f][xrow&2047]
#pragma unroll
                    for (int reg = 0; reg < 4; reg++)
                        vtout[((size_t)(xrow >> 11) * 1024 + cf + reg) * S_LEN +
                              (xrow & 2047)] = f2bf(acc[mi][ni][reg] + b4[reg]);
                }
            }
        }
    }
}

// ---------------------------------------------------------------------------
// Flash attention, causal, no-max exp2 softmax. Paired q-tiles (pi,31-pi),
// 64-key tiles. S computed TRANSPOSED (A=K,B=Q) so col=q(l16), row=key:
// P stays in registers as the B-operand of mfma_f32_16x16x16_bf16 for PV
// (O^T accumulated; no P LDS round-trip). Ks/Vs XOR-swizzled.
// ---------------------------------------------------------------------------
__global__ __launch_bounds__(256) void attn_kernel(const u16* __restrict__ Qg,
                                                   const u16* __restrict__ Kg,
                                                   const u16* __restrict__ Vt,
                                                   u16* __restrict__ Og) {
    __shared__ __align__(16) u16 Ks[2][64][32]; // [d-half][key][d%32 swz]
    __shared__ __align__(16) u16 Vs[2][64][32]; // [key-half][d][key%32 swz]

    const int t = threadIdx.x, lane = t & 63, w = t >> 6;
    const int quad = lane >> 4, l16 = lane & 15;
    const int pi = blockIdx.x;
    const int bh = blockIdx.y, b = bh >> 4, h = bh & 15;
    const size_t base = (size_t)b * S_LEN * DMODEL + h * 64;
    const size_t vbase = ((size_t)b * 1024 + h * 64) * S_LEN;
    const int sr = t >> 2, sc = (t & 3) * 16;
    const int pl = sc >> 5;                // plane
    const int g0 = (sc >> 3) & 3;          // first 8-elem slot
    const int ss = (sr >> 1) & 3;          // staging swizzle
    const int swz = (l16 >> 1) & 3;        // frag-read swizzle

    const u16* kp = Kg + base + (size_t)sr * DMODEL + sc;
    const u16* vp = Vt + vbase + (size_t)sr * S_LEN + sc;
    uint4 k0r = *(const uint4*)kp, k1r = *(const uint4*)(kp + 8);
    uint4 v0r = *(const uint4*)vp, v1r = *(const uint4*)(vp + 8);

#pragma unroll
    for (int seg = 0; seg < 2; seg++) {
        const int qt = seg == 0 ? pi : 31 - pi;
        const int niter = qt + 1;
        const int q0 = qt * 64;

        bf8 aq[2]; // Q-frag (B-operand: lane n=q=l16, k=d=c*32+quad*8+j)
#pragma unroll
        for (int c = 0; c < 2; c++)
            aq[c] = *(const bf8*)(Qg + base +
                (size_t)(q0 + w * 16 + l16) * DMODEL + c * 32 + quad * 8);

        float lsum = 0.f;    // per-lane: q = l16
        f32x4 oT[4] = {};    // O^T: col=q=l16, row=d=ds*16+quad*4+reg

        for (int kt = 0; kt < niter; kt++) {
            __syncthreads();
            *(uint4*)&Ks[pl][sr][(g0 ^ ss) * 8] = k0r;
            *(uint4*)&Ks[pl][sr][((g0 + 1) ^ ss) * 8] = k1r;
            *(uint4*)&Vs[pl][sr][(g0 ^ ss) * 8] = v0r;
            *(uint4*)&Vs[pl][sr][((g0 + 1) ^ ss) * 8] = v1r;
            __syncthreads();
            // prefetch next K/V tile (next kt, or tile 0 of segment B)
            if (!(seg == 1 && kt + 1 == niter)) {
                int nt = (kt + 1 < niter) ? kt + 1 : 0;
                size_t ok = (size_t)nt * 64 * DMODEL;
                int ov = nt * 64;
                k0r = *(const uint4*)(kp + ok); k1r = *(const uint4*)(kp + ok + 8);
                v0r = *(const uint4*)(vp + ov); v1r = *(const uint4*)(vp + ov + 8);
            }

            // S^T = (K Q^T): A=K-frag (m=key=l16), B=Q-frag.
            // scv[ns]: col=q=l16, row=key=ns*16+quad*4+reg
            f32x4 scv[4] = {};
#pragma unroll
            for (int c = 0; c < 2; c++)
#pragma unroll
                for (int ns = 0; ns < 4; ns++) {
                    bf8 ak = *(const bf8*)&Ks[c][ns * 16 + l16][(quad ^ swz) * 8];
                    scv[ns] = __builtin_amdgcn_mfma_f32_16x16x32_bf16(
                        ak, aq[c], scv[ns], 0, 0, 0);
                }

            // exp2 (scale*log2e folded in Q); diag-tile causal mask; pack P
            // in-register; PV via 16x16x16 (A=V^T b64 frag, B=P^T regs).
            const bool diag = (kt == qt);
            const int ql = w * 16 + l16; // tile-local q
#pragma unroll
            for (int ns = 0; ns < 4; ns++) {
                float p[4];
#pragma unroll
                for (int r = 0; r < 4; r++) {
                    int key = ns * 16 + quad * 4 + r;
                    p[r] = (diag && key > ql) ? 0.f
                                              : __builtin_amdgcn_exp2f(scv[ns][r]);
                    lsum += p[r];
                }
                union { unsigned u[2]; bf4 v; } pk;
                pk.u[0] = (__float_as_uint(p[0]) >> 16) |
                          (__float_as_uint(p[1]) & 0xffff0000u);
                pk.u[1] = (__float_as_uint(p[2]) >> 16) |
                          (__float_as_uint(p[3]) & 0xffff0000u);
#pragma unroll
                for (int ds = 0; ds < 4; ds++) {
                    bf4 av = *(const bf4*)&Vs[ns >> 1][ds * 16 + l16]
                        [((((ns & 1) * 2 + (quad >> 1)) ^ swz) * 8) + (quad & 1) * 4];
                    oT[ds] = __builtin_amdgcn_mfma_f32_16x16x16bf16_1k(
                        av, pk.v, oT[ds], 0, 0, 0);
                }
            }
        }

        // epilogue: reduce l across quads, normalize, packed store
        float l = lsum;
        l += __shfl_xor(l, 16, 64);
        l += __shfl_xor(l, 32, 64);
        const float inv = 1.f / l;
        const int qq = q0 + w * 16 + l16;
#pragma unroll
        for (int ds = 0; ds < 4; ds++) {
            u16 t4[4];
#pragma unroll
            for (int r = 0; r < 4; r++) t4[r] = f2bf(oT[ds][r] * inv);
            *(uint2*)(Og + base + (size_t)qq * DMODEL + ds * 16 + quad * 4) =
                *(uint2*)t4;
        }
    }
}

// ---------------------------------------------------------------------------
// Workspace: d_ws 32MB = wT(8) | qb(8) | kb(8) | ob(8).
// Transients xb/vt live inside d_out (16MB), dead before O-proj writes it.
// ---------------------------------------------------------------------------
extern "C" void kernel_launch(void* const* d_in, const int* in_sizes, int n_in,
                              void* d_out, int out_size, void* d_ws, size_t ws_size,
                              hipStream_t stream) {
    const float* x  = (const float*)d_in[0];
    const float* wq = (const float*)d_in[1];
    const float* bq = (const float*)d_in[2];
    const float* wk = (const float*)d_in[3];
    const float* bk = (const float*)d_in[4];
    const float* wv = (const float*)d_in[5];
    const float* bv = (const float*)d_in[6];
    const float* wo = (const float*)d_in[7];
    const float* bo = (const float*)d_in[8];
    float* out = (float*)d_out;

    const size_t E = (size_t)MROWS * DMODEL; // 4M elems
    u16* xb  = (u16*)d_out;      // bf16 x (dead after QKV GEMM)
    u16* vt  = xb + E;           // V^T (dead after attn)
    u16* wT  = (u16*)d_ws;       // wqT|wkT|wvT|woT
    u16* woT = wT + 3145728;
    u16* qb  = wT + 4194304;
    u16* kb  = qb + E;
    u16* ob  = kb + E;

    dim3 blk(256);
    prep_kernel<<<3072, blk, 0, stream>>>(x, xb, wq, wk, wv, wo, wT);

    // fused QKV: N=3072, Q scale = log2e/8
    gemm_mfma<0><<<dim3(24, 32), blk, 0, stream>>>(
        xb, wT, bq, bk, bv, qb, kb, vt, nullptr, 0.18033688011112042f);

    dim3 agrid(16, BATCH * NHEADS); // paired q-tiles, uniform 33 iters/block
    attn_kernel<<<agrid, blk, 0, stream>>>(qb, kb, vt, ob);

    // O-proj: 64x128 tiles, 512 blocks, fp32 float4 stores
    gemm_mfma<1><<<dim3(8, 64), blk, 0, stream>>>(
        ob, woT, bo, nullptr, nullptr, nullptr, nullptr, nullptr, out, 1.0f);
}

// Round 11
// 192.378 us; speedup vs baseline: 1.2222x; 1.0260x over previous
//
#include <hip/hip_runtime.h>
#include <math.h>

#define S_LEN 2048
#define BATCH 2
#define DMODEL 1024
#define NHEADS 16
#define MROWS 4096

typedef short bf8 __attribute__((ext_vector_type(8)));   // 8 x bf16
typedef short bf4 __attribute__((ext_vector_type(4)));   // 4 x bf16
typedef float f32x4 __attribute__((ext_vector_type(4))); // MFMA accumulator
typedef unsigned short u16;

static __device__ inline u16 f2bf(float f) {
    union { float f; unsigned u; } v; v.f = f;
    unsigned r = v.u + 0x7fffu + ((v.u >> 16) & 1u); // RNE
    return (u16)(r >> 16);
}

// async global->LDS DMA, 16B per lane. LDS dest = (wave-uniform base) + lane*16.
static __device__ inline void load16(const void* g, void* l) {
    __builtin_amdgcn_global_load_lds(
        (const __attribute__((address_space(1))) unsigned int*)g,
        (__attribute__((address_space(3))) unsigned int*)l, 16, 0, 0);
}

// ---------------------------------------------------------------------------
// Fused prep: blocks [0,2048) convert x fp32->bf16; [2048,3072) transpose
// the 4 weights to Wt[n][k] bf16.
// ---------------------------------------------------------------------------
__global__ __launch_bounds__(256) void prep_kernel(
    const float* __restrict__ x, u16* __restrict__ xb,
    const float* __restrict__ W0, const float* __restrict__ W1,
    const float* __restrict__ W2, const float* __restrict__ W3,
    u16* __restrict__ wT) {
    const int bx = blockIdx.x, t = threadIdx.x;
    if (bx < 2048) {
        int i = bx * 256 + t;
        const float4* p = (const float4*)x + (size_t)i * 2;
        float4 a = p[0], b = p[1];
        u16 tmp[8] = {f2bf(a.x), f2bf(a.y), f2bf(a.z), f2bf(a.w),
                      f2bf(b.x), f2bf(b.y), f2bf(b.z), f2bf(b.w)};
        ((uint4*)xb)[i] = *(uint4*)tmp;
        return;
    }
    __shared__ u16 Ls[64][65];
    const int id = bx - 2048;
    const int z = id >> 8, rem = id & 255;
    const int n0 = (rem & 15) * 64, k0 = (rem >> 4) * 64;
    const float* W = z == 0 ? W0 : z == 1 ? W1 : z == 2 ? W2 : W3;
    u16* Wt = wT + (size_t)z * 1024 * 1024;
    const int r = t >> 2, c4 = (t & 3) * 16;
    const float* p = W + (size_t)(k0 + r) * 1024 + n0 + c4;
#pragma unroll
    for (int i = 0; i < 16; i += 4) {
        float4 v = *(const float4*)(p + i);
        Ls[r][c4 + i + 0] = f2bf(v.x);
        Ls[r][c4 + i + 1] = f2bf(v.y);
        Ls[r][c4 + i + 2] = f2bf(v.z);
        Ls[r][c4 + i + 3] = f2bf(v.w);
    }
    __syncthreads();
    u16 tmp[16];
#pragma unroll
    for (int i = 0; i < 16; i++) tmp[i] = Ls[c4 + i][r];
    uint4* q = (uint4*)(Wt + (size_t)(n0 + r) * 1024 + k0 + c4);
    q[0] = *(uint4*)tmp;
    q[1] = *(uint4*)(tmp + 8);
}

// ---------------------------------------------------------------------------
// Swapped-operand MFMA GEMM, BK=64 (16 barrier-pairs, 32 MFMA each).
// LDS rows are 64 elems (128B); XOR swizzle slot=(kc*4+quad)^(l16&7) -> 2-way.
// MODE 0: QKV. 128 xrows x 128 features, grid (24,32).
// MODE 1: O-proj. 64 xrows x 128 features, grid (8,64). fp32 float4 out.
// ---------------------------------------------------------------------------
template <int MODE>
__global__ __launch_bounds__(256) void gemm_mfma(
    const u16* __restrict__ A, const u16* __restrict__ Bt,
    const float* __restrict__ bqp, const float* __restrict__ bkp,
    const float* __restrict__ bvp,
    u16* __restrict__ qout, u16* __restrict__ kout, u16* __restrict__ vtout,
    float* __restrict__ fout, float qscale) {
    constexpr int TM = (MODE == 1) ? 64 : 128; // xrows per block
    constexpr int MI = (MODE == 1) ? 2 : 4;    // feature groups per wave
    constexpr int ADMA = (MODE == 1) ? 2 : 4;  // A-DMAs per wave per iter
    __shared__ __align__(16) u16 As[TM * 64];  // x rows
    __shared__ __align__(16) u16 Bs[128 * 64]; // W rows (features)

    const int t = threadIdx.x, lane = t & 63, w = t >> 6;
    const int quad = lane >> 4, l16 = lane & 15;
    const int row0 = blockIdx.y * TM, col0 = blockIdx.x * 128;
    const int fq = (MODE == 1) ? w * 32 : (w & 1) * 64;
    const int xq = (MODE == 1) ? 0 : (w >> 1) * 64;
    const int K = DMODEL;

    const int lrow = lane >> 3;                        // 0..7
    const int koff = ((lane & 7) ^ lrow) * 8;          // swizzled k-group
    const int abase = (MODE == 1) ? w * 16 : w * 32;
    const u16* ag = A + (size_t)(row0 + abase + lrow) * K + koff;
    const u16* bg = Bt + (size_t)(col0 + w * 32 + lrow) * K + koff;
    u16* lA = As + abase * 64;
    u16* lB = Bs + (w * 32) * 64;
    const int swz = l16 & 7;

    f32x4 acc[MI][4] = {};

    for (int k0 = 0; k0 < K; k0 += 64) {
#pragma unroll
        for (int d = 0; d < ADMA; d++)
            load16(ag + (size_t)d * 8 * K + k0, lA + d * 512);
#pragma unroll
        for (int d = 0; d < 4; d++)
            load16(bg + (size_t)d * 8 * K + k0, lB + d * 512);
        __syncthreads(); // drains vmcnt -> LDS valid
#pragma unroll
        for (int kc = 0; kc < 2; kc++) {
            bf8 xf[4], wf[MI];
#pragma unroll
            for (int ni = 0; ni < 4; ni++)
                xf[ni] = *(const bf8*)&As[(xq + ni * 16 + l16) * 64 +
                                          ((kc * 4 + quad) ^ swz) * 8];
#pragma unroll
            for (int mi = 0; mi < MI; mi++)
                wf[mi] = *(const bf8*)&Bs[(fq + mi * 16 + l16) * 64 +
                                          ((kc * 4 + quad) ^ swz) * 8];
#pragma unroll
            for (int mi = 0; mi < MI; mi++)
#pragma unroll
                for (int ni = 0; ni < 4; ni++)
                    acc[mi][ni] = __builtin_amdgcn_mfma_f32_16x16x32_bf16(
                        wf[mi], xf[ni], acc[mi][ni], 0, 0, 0);
        }
        __syncthreads(); // reads done before next DMA overwrites
    }

    const int sect = (col0 + fq) >> 10; // uniform per wave
#pragma unroll
    for (int mi = 0; mi < MI; mi++) {
        const int featb = col0 + fq + mi * 16 + quad * 4;
        float b4[4];
#pragma unroll
        for (int reg = 0; reg < 4; reg++)
            b4[reg] = (MODE == 1 ? bqp : (sect == 0 ? bqp : sect == 1 ? bkp : bvp))
                          [(featb + reg) & 1023];
#pragma unroll
        for (int ni = 0; ni < 4; ni++) {
            const int xrow = row0 + xq + ni * 16 + l16;
            if (MODE == 1) {
                float4 o;
                o.x = acc[mi][ni][0] + b4[0];
                o.y = acc[mi][ni][1] + b4[1];
                o.z = acc[mi][ni][2] + b4[2];
                o.w = acc[mi][ni][3] + b4[3];
                *(float4*)(fout + (size_t)xrow * 1024 + featb) = o;
            } else {
                const int cf = featb & 1023;
                if (sect == 0) {
                    u16 t4[4];
#pragma unroll
                    for (int reg = 0; reg < 4; reg++)
                        t4[reg] = f2bf((acc[mi][ni][reg] + b4[reg]) * qscale);
                    *(uint2*)(qout + (size_t)xrow * 1024 + cf) = *(uint2*)t4;
                } else if (sect == 1) {
                    u16 t4[4];
#pragma unroll
                    for (int reg = 0; reg < 4; reg++)
                        t4[reg] = f2bf(acc[mi][ni][reg] + b4[reg]);
                    *(uint2*)(kout + (size_t)xrow * 1024 + cf) = *(uint2*)t4;
                } else { // V^T: Vt[(xrow>>11)*1024 + f][xrow&2047]
#pragma unroll
                    for (int reg = 0; reg < 4; reg++)
                        vtout[((size_t)(xrow >> 11) * 1024 + cf + reg) * S_LEN +
                              (xrow & 2047)] = f2bf(acc[mi][ni][reg] + b4[reg]);
                }
            }
        }
    }
}

// ---------------------------------------------------------------------------
// Flash attention, causal, no-max exp2 softmax. Paired q-tiles (pi,31-pi),
// 64-key tiles. S computed TRANSPOSED (A=K,B=Q); P stays in registers as the
// B-operand of mfma 16x16x16 for PV (no P LDS round trip).
// XCD-locality grid: blockIdx.x = bh (32), blockIdx.y = pi (16) -> linear
// id = bh + 32*pi -> XCD = bh%8: all pi-blocks of one head share an XCD's L2
// (4 heads/XCD x 512KB K/V = 2MB < 4MB L2). Kills the 8x K/V HBM refetch.
// ---------------------------------------------------------------------------
__global__ __launch_bounds__(256) void attn_kernel(const u16* __restrict__ Qg,
                                                   const u16* __restrict__ Kg,
                                                   const u16* __restrict__ Vt,
                                                   u16* __restrict__ Og) {
    __shared__ __align__(16) u16 Ks[2][64][32]; // [d-half][key][d%32 swz]
    __shared__ __align__(16) u16 Vs[2][64][32]; // [key-half][d][key%32 swz]

    const int t = threadIdx.x, lane = t & 63, w = t >> 6;
    const int quad = lane >> 4, l16 = lane & 15;
    const int pi = blockIdx.y;                 // paired q-tile index
    const int bh = blockIdx.x, b = bh >> 4, h = bh & 15;
    const size_t base = (size_t)b * S_LEN * DMODEL + h * 64;
    const size_t vbase = ((size_t)b * 1024 + h * 64) * S_LEN;
    const int sr = t >> 2, sc = (t & 3) * 16;
    const int pl = sc >> 5;                // plane
    const int g0 = (sc >> 3) & 3;          // first 8-elem slot
    const int ss = (sr >> 1) & 3;          // staging swizzle
    const int swz = (l16 >> 1) & 3;        // frag-read swizzle

    const u16* kp = Kg + base + (size_t)sr * DMODEL + sc;
    const u16* vp = Vt + vbase + (size_t)sr * S_LEN + sc;
    uint4 k0r = *(const uint4*)kp, k1r = *(const uint4*)(kp + 8);
    uint4 v0r = *(const uint4*)vp, v1r = *(const uint4*)(vp + 8);

#pragma unroll
    for (int seg = 0; seg < 2; seg++) {
        const int qt = seg == 0 ? pi : 31 - pi;
        const int niter = qt + 1;
        const int q0 = qt * 64;

        bf8 aq[2]; // Q-frag (B-operand: lane n=q=l16, k=d=c*32+quad*8+j)
#pragma unroll
        for (int c = 0; c < 2; c++)
            aq[c] = *(const bf8*)(Qg + base +
                (size_t)(q0 + w * 16 + l16) * DMODEL + c * 32 + quad * 8);

        float lsum = 0.f;    // per-lane: q = l16
        f32x4 oT[4] = {};    // O^T: col=q=l16, row=d=ds*16+quad*4+reg

        for (int kt = 0; kt < niter; kt++) {
            __syncthreads();
            *(uint4*)&Ks[pl][sr][(g0 ^ ss) * 8] = k0r;
            *(uint4*)&Ks[pl][sr][((g0 + 1) ^ ss) * 8] = k1r;
            *(uint4*)&Vs[pl][sr][(g0 ^ ss) * 8] = v0r;
            *(uint4*)&Vs[pl][sr][((g0 + 1) ^ ss) * 8] = v1r;
            __syncthreads();
            // prefetch next K/V tile (next kt, or tile 0 of segment B)
            if (!(seg == 1 && kt + 1 == niter)) {
                int nt = (kt + 1 < niter) ? kt + 1 : 0;
                size_t ok = (size_t)nt * 64 * DMODEL;
                int ov = nt * 64;
                k0r = *(const uint4*)(kp + ok); k1r = *(const uint4*)(kp + ok + 8);
                v0r = *(const uint4*)(vp + ov); v1r = *(const uint4*)(vp + ov + 8);
            }

            // S^T = (K Q^T): A=K-frag (m=key=l16), B=Q-frag.
            // scv[ns]: col=q=l16, row=key=ns*16+quad*4+reg
            f32x4 scv[4] = {};
#pragma unroll
            for (int c = 0; c < 2; c++)
#pragma unroll
                for (int ns = 0; ns < 4; ns++) {
                    bf8 ak = *(const bf8*)&Ks[c][ns * 16 + l16][(quad ^ swz) * 8];
                    scv[ns] = __builtin_amdgcn_mfma_f32_16x16x32_bf16(
                        ak, aq[c], scv[ns], 0, 0, 0);
                }

            // exp2 (scale*log2e folded in Q); diag-tile causal mask; pack P
            // in-register; PV via 16x16x16 (A=V^T b64 frag, B=P^T regs).
            const bool diag = (kt == qt);
            const int ql = w * 16 + l16; // tile-local q
#pragma unroll
            for (int ns = 0; ns < 4; ns++) {
                float p[4];
#pragma unroll
                for (int r = 0; r < 4; r++) {
                    int key = ns * 16 + quad * 4 + r;
                    p[r] = (diag && key > ql) ? 0.f
                                              : __builtin_amdgcn_exp2f(scv[ns][r]);
                    lsum += p[r];
                }
                union { unsigned u[2]; bf4 v; } pk;
                pk.u[0] = (__float_as_uint(p[0]) >> 16) |
                          (__float_as_uint(p[1]) & 0xffff0000u);
                pk.u[1] = (__float_as_uint(p[2]) >> 16) |
                          (__float_as_uint(p[3]) & 0xffff0000u);
#pragma unroll
                for (int ds = 0; ds < 4; ds++) {
                    bf4 av = *(const bf4*)&Vs[ns >> 1][ds * 16 + l16]
                        [((((ns & 1) * 2 + (quad >> 1)) ^ swz) * 8) + (quad & 1) * 4];
                    oT[ds] = __builtin_amdgcn_mfma_f32_16x16x16bf16_1k(
                        av, pk.v, oT[ds], 0, 0, 0);
                }
            }
        }

        // epilogue: reduce l across quads, normalize, packed store
        float l = lsum;
        l += __shfl_xor(l, 16, 64);
        l += __shfl_xor(l, 32, 64);
        const float inv = 1.f / l;
        const int qq = q0 + w * 16 + l16;
#pragma unroll
        for (int ds = 0; ds < 4; ds++) {
            u16 t4[4];
#pragma unroll
            for (int r = 0; r < 4; r++) t4[r] = f2bf(oT[ds][r] * inv);
            *(uint2*)(Og + base + (size_t)qq * DMODEL + ds * 16 + quad * 4) =
                *(uint2*)t4;
        }
    }
}

// ---------------------------------------------------------------------------
// Workspace: d_ws 32MB = wT(8) | qb(8) | kb(8) | ob(8).
// Transients xb/vt live inside d_out (16MB), dead before O-proj writes it.
// ---------------------------------------------------------------------------
extern "C" void kernel_launch(void* const* d_in, const int* in_sizes, int n_in,
                              void* d_out, int out_size, void* d_ws, size_t ws_size,
                              hipStream_t stream) {
    const float* x  = (const float*)d_in[0];
    const float* wq = (const float*)d_in[1];
    const float* bq = (const float*)d_in[2];
    const float* wk = (const float*)d_in[3];
    const float* bk = (const float*)d_in[4];
    const float* wv = (const float*)d_in[5];
    const float* bv = (const float*)d_in[6];
    const float* wo = (const float*)d_in[7];
    const float* bo = (const float*)d_in[8];
    float* out = (float*)d_out;

    const size_t E = (size_t)MROWS * DMODEL; // 4M elems
    u16* xb  = (u16*)d_out;      // bf16 x (dead after QKV GEMM)
    u16* vt  = xb + E;           // V^T (dead after attn)
    u16* wT  = (u16*)d_ws;       // wqT|wkT|wvT|woT
    u16* woT = wT + 3145728;
    u16* qb  = wT + 4194304;
    u16* kb  = qb + E;
    u16* ob  = kb + E;

    dim3 blk(256);
    prep_kernel<<<3072, blk, 0, stream>>>(x, xb, wq, wk, wv, wo, wT);

    // fused QKV: N=3072, Q scale = log2e/8
    gemm_mfma<0><<<dim3(24, 32), blk, 0, stream>>>(
        xb, wT, bq, bk, bv, qb, kb, vt, nullptr, 0.18033688011112042f);

    // XCD-locality grid: x = bh (32), y = paired q-tile (16)
    dim3 agrid(BATCH * NHEADS, 16);
    attn_kernel<<<agrid, blk, 0, stream>>>(qb, kb, vt, ob);

    // O-proj: 64x128 tiles, 512 blocks, fp32 float4 stores
    gemm_mfma<1><<<dim3(8, 64), blk, 0, stream>>>(
        ob, woT, bo, nullptr, nullptr, nullptr, nullptr, nullptr, out, 1.0f);
}

// Round 12
// 192.043 us; speedup vs baseline: 1.2243x; 1.0017x over previous
//
#include <hip/hip_runtime.h>
#include <math.h>

#define S_LEN 2048
#define BATCH 2
#define DMODEL 1024
#define NHEADS 16
#define MROWS 4096

typedef short bf8 __attribute__((ext_vector_type(8)));   // 8 x bf16
typedef short bf4 __attribute__((ext_vector_type(4)));   // 4 x bf16
typedef float f32x4 __attribute__((ext_vector_type(4))); // MFMA accumulator
typedef unsigned short u16;

static __device__ inline u16 f2bf(float f) {
    union { float f; unsigned u; } v; v.f = f;
    unsigned r = v.u + 0x7fffu + ((v.u >> 16) & 1u); // RNE
    return (u16)(r >> 16);
}

// async global->LDS DMA, 16B per lane. LDS dest = (wave-uniform base) + lane*16.
static __device__ inline void load16(const void* g, void* l) {
    __builtin_amdgcn_global_load_lds(
        (const __attribute__((address_space(1))) unsigned int*)g,
        (__attribute__((address_space(3))) unsigned int*)l, 16, 0, 0);
}

// ---------------------------------------------------------------------------
// Fused prep: blocks [0,2048) convert x fp32->bf16; [2048,3072) transpose
// the 4 weights to Wt[n][k] bf16.
// ---------------------------------------------------------------------------
__global__ __launch_bounds__(256) void prep_kernel(
    const float* __restrict__ x, u16* __restrict__ xb,
    const float* __restrict__ W0, const float* __restrict__ W1,
    const float* __restrict__ W2, const float* __restrict__ W3,
    u16* __restrict__ wT) {
    const int bx = blockIdx.x, t = threadIdx.x;
    if (bx < 2048) {
        int i = bx * 256 + t;
        const float4* p = (const float4*)x + (size_t)i * 2;
        float4 a = p[0], b = p[1];
        u16 tmp[8] = {f2bf(a.x), f2bf(a.y), f2bf(a.z), f2bf(a.w),
                      f2bf(b.x), f2bf(b.y), f2bf(b.z), f2bf(b.w)};
        ((uint4*)xb)[i] = *(uint4*)tmp;
        return;
    }
    __shared__ u16 Ls[64][65];
    const int id = bx - 2048;
    const int z = id >> 8, rem = id & 255;
    const int n0 = (rem & 15) * 64, k0 = (rem >> 4) * 64;
    const float* W = z == 0 ? W0 : z == 1 ? W1 : z == 2 ? W2 : W3;
    u16* Wt = wT + (size_t)z * 1024 * 1024;
    const int r = t >> 2, c4 = (t & 3) * 16;
    const float* p = W + (size_t)(k0 + r) * 1024 + n0 + c4;
#pragma unroll
    for (int i = 0; i < 16; i += 4) {
        float4 v = *(const float4*)(p + i);
        Ls[r][c4 + i + 0] = f2bf(v.x);
        Ls[r][c4 + i + 1] = f2bf(v.y);
        Ls[r][c4 + i + 2] = f2bf(v.z);
        Ls[r][c4 + i + 3] = f2bf(v.w);
    }
    __syncthreads();
    u16 tmp[16];
#pragma unroll
    for (int i = 0; i < 16; i++) tmp[i] = Ls[c4 + i][r];
    uint4* q = (uint4*)(Wt + (size_t)(n0 + r) * 1024 + k0 + c4);
    q[0] = *(uint4*)tmp;
    q[1] = *(uint4*)(tmp + 8);
}

// ---------------------------------------------------------------------------
// Double-buffered swapped-operand MFMA GEMM. 64 xrows x 128 features per
// block, BK=64. Pipeline: barrier -> issue DMA(next, other buf) -> compute.
// One barrier/iter; DMA flight overlaps compute. XOR-swizzled LDS (0-conflict,
// R8-verified). 4 waves: wave w owns features [w*32, w*32+32), all 64 xrows.
// MODE 0: QKV (grid 24x64): sect 0->Q bf16*qscale, 1->K bf16, 2->V^T scatter
// MODE 1: O-proj (grid 8x64): fp32 float4 out + bias
// ---------------------------------------------------------------------------
template <int MODE>
__global__ __launch_bounds__(256) void gemm_mfma(
    const u16* __restrict__ A, const u16* __restrict__ Bt,
    const float* __restrict__ bqp, const float* __restrict__ bkp,
    const float* __restrict__ bvp,
    u16* __restrict__ qout, u16* __restrict__ kout, u16* __restrict__ vtout,
    float* __restrict__ fout, float qscale) {
    __shared__ __align__(16) u16 As[2][64 * 64];  // x rows
    __shared__ __align__(16) u16 Bs[2][128 * 64]; // W rows (features)

    const int t = threadIdx.x, lane = t & 63, w = t >> 6;
    const int quad = lane >> 4, l16 = lane & 15;
    const int row0 = blockIdx.y * 64, col0 = blockIdx.x * 128;
    const int K = DMODEL;

    const int lrow = lane >> 3;               // 0..7
    const int koff = ((lane & 7) ^ lrow) * 8; // swizzled k-group (global side)
    const u16* ag = A + (size_t)(row0 + w * 16 + lrow) * K + koff;
    const u16* bg = Bt + (size_t)(col0 + w * 32 + lrow) * K + koff;
    const int swz = l16 & 7;

    f32x4 acc[2][4] = {};

    // prologue: stage k0=0 into buffer 0
    {
        u16* lA = As[0] + (w * 16) * 64;
        u16* lB = Bs[0] + (w * 32) * 64;
        load16(ag, lA);
        load16(ag + (size_t)8 * K, lA + 512);
#pragma unroll
        for (int d = 0; d < 4; d++)
            load16(bg + (size_t)d * 8 * K, lB + d * 512);
    }

#pragma unroll 2
    for (int it = 0; it < 16; it++) {
        const int buf = it & 1;
        __syncthreads(); // current buf's DMA landed; prior reads of other buf done
        if (it + 1 < 16) { // prefetch next k-slab into the other buffer
            const int k0 = (it + 1) * 64;
            u16* lA = As[buf ^ 1] + (w * 16) * 64;
            u16* lB = Bs[buf ^ 1] + (w * 32) * 64;
            load16(ag + k0, lA);
            load16(ag + (size_t)8 * K + k0, lA + 512);
#pragma unroll
            for (int d = 0; d < 4; d++)
                load16(bg + (size_t)d * 8 * K + k0, lB + d * 512);
        }
#pragma unroll
        for (int kc = 0; kc < 2; kc++) {
            bf8 xf[4], wf[2];
#pragma unroll
            for (int ni = 0; ni < 4; ni++)
                xf[ni] = *(const bf8*)&As[buf][(ni * 16 + l16) * 64 +
                                              ((kc * 4 + quad) ^ swz) * 8];
#pragma unroll
            for (int mi = 0; mi < 2; mi++)
                wf[mi] = *(const bf8*)&Bs[buf][(w * 32 + mi * 16 + l16) * 64 +
                                              ((kc * 4 + quad) ^ swz) * 8];
#pragma unroll
            for (int mi = 0; mi < 2; mi++)
#pragma unroll
                for (int ni = 0; ni < 4; ni++)
                    acc[mi][ni] = __builtin_amdgcn_mfma_f32_16x16x32_bf16(
                        wf[mi], xf[ni], acc[mi][ni], 0, 0, 0);
        }
    }

    const int sect = (col0 + w * 32) >> 10; // uniform per wave
#pragma unroll
    for (int mi = 0; mi < 2; mi++) {
        const int featb = col0 + w * 32 + mi * 16 + quad * 4;
        float b4[4];
#pragma unroll
        for (int reg = 0; reg < 4; reg++)
            b4[reg] = (MODE == 1 ? bqp : (sect == 0 ? bqp : sect == 1 ? bkp : bvp))
                          [(featb + reg) & 1023];
#pragma unroll
        for (int ni = 0; ni < 4; ni++) {
            const int xrow = row0 + ni * 16 + l16;
            if (MODE == 1) {
                float4 o;
                o.x = acc[mi][ni][0] + b4[0];
                o.y = acc[mi][ni][1] + b4[1];
                o.z = acc[mi][ni][2] + b4[2];
                o.w = acc[mi][ni][3] + b4[3];
                *(float4*)(fout + (size_t)xrow * 1024 + featb) = o;
            } else {
                const int cf = featb & 1023;
                if (sect == 0) {
                    u16 t4[4];
#pragma unroll
                    for (int reg = 0; reg < 4; reg++)
                        t4[reg] = f2bf((acc[mi][ni][reg] + b4[reg]) * qscale);
                    *(uint2*)(qout + (size_t)xrow * 1024 + cf) = *(uint2*)t4;
                } else if (sect == 1) {
                    u16 t4[4];
#pragma unroll
                    for (int reg = 0; reg < 4; reg++)
                        t4[reg] = f2bf(acc[mi][ni][reg] + b4[reg]);
                    *(uint2*)(kout + (size_t)xrow * 1024 + cf) = *(uint2*)t4;
                } else { // V^T: Vt[(xrow>>11)*1024 + f][xrow&2047]
#pragma unroll
                    for (int reg = 0; reg < 4; reg++)
                        vtout[((size_t)(xrow >> 11) * 1024 + cf + reg) * S_LEN +
                              (xrow & 2047)] = f2bf(acc[mi][ni][reg] + b4[reg]);
                }
            }
        }
    }
}

// ---------------------------------------------------------------------------
// Flash attention (unchanged from R11): causal, no-max exp2 softmax, paired
// q-tiles, S^T via A=K/B=Q, register-P PV via mfma 16x16x16, XCD-local grid.
// ---------------------------------------------------------------------------
__global__ __launch_bounds__(256) void attn_kernel(const u16* __restrict__ Qg,
                                                   const u16* __restrict__ Kg,
                                                   const u16* __restrict__ Vt,
                                                   u16* __restrict__ Og) {
    __shared__ __align__(16) u16 Ks[2][64][32]; // [d-half][key][d%32 swz]
    __shared__ __align__(16) u16 Vs[2][64][32]; // [key-half][d][key%32 swz]

    const int t = threadIdx.x, lane = t & 63, w = t >> 6;
    const int quad = lane >> 4, l16 = lane & 15;
    const int pi = blockIdx.y;                 // paired q-tile index
    const int bh = blockIdx.x, b = bh >> 4, h = bh & 15;
    const size_t base = (size_t)b * S_LEN * DMODEL + h * 64;
    const size_t vbase = ((size_t)b * 1024 + h * 64) * S_LEN;
    const int sr = t >> 2, sc = (t & 3) * 16;
    const int pl = sc >> 5;
    const int g0 = (sc >> 3) & 3;
    const int ss = (sr >> 1) & 3;
    const int swz = (l16 >> 1) & 3;

    const u16* kp = Kg + base + (size_t)sr * DMODEL + sc;
    const u16* vp = Vt + vbase + (size_t)sr * S_LEN + sc;
    uint4 k0r = *(const uint4*)kp, k1r = *(const uint4*)(kp + 8);
    uint4 v0r = *(const uint4*)vp, v1r = *(const uint4*)(vp + 8);

#pragma unroll
    for (int seg = 0; seg < 2; seg++) {
        const int qt = seg == 0 ? pi : 31 - pi;
        const int niter = qt + 1;
        const int q0 = qt * 64;

        bf8 aq[2]; // Q-frag (B-operand: lane n=q=l16, k=d=c*32+quad*8+j)
#pragma unroll
        for (int c = 0; c < 2; c++)
            aq[c] = *(const bf8*)(Qg + base +
                (size_t)(q0 + w * 16 + l16) * DMODEL + c * 32 + quad * 8);

        float lsum = 0.f;    // per-lane: q = l16
        f32x4 oT[4] = {};    // O^T: col=q=l16, row=d=ds*16+quad*4+reg

        for (int kt = 0; kt < niter; kt++) {
            __syncthreads();
            *(uint4*)&Ks[pl][sr][(g0 ^ ss) * 8] = k0r;
            *(uint4*)&Ks[pl][sr][((g0 + 1) ^ ss) * 8] = k1r;
            *(uint4*)&Vs[pl][sr][(g0 ^ ss) * 8] = v0r;
            *(uint4*)&Vs[pl][sr][((g0 + 1) ^ ss) * 8] = v1r;
            __syncthreads();
            if (!(seg == 1 && kt + 1 == niter)) {
                int nt = (kt + 1 < niter) ? kt + 1 : 0;
                size_t ok = (size_t)nt * 64 * DMODEL;
                int ov = nt * 64;
                k0r = *(const uint4*)(kp + ok); k1r = *(const uint4*)(kp + ok + 8);
                v0r = *(const uint4*)(vp + ov); v1r = *(const uint4*)(vp + ov + 8);
            }

            f32x4 scv[4] = {};
#pragma unroll
            for (int c = 0; c < 2; c++)
#pragma unroll
                for (int ns = 0; ns < 4; ns++) {
                    bf8 ak = *(const bf8*)&Ks[c][ns * 16 + l16][(quad ^ swz) * 8];
                    scv[ns] = __builtin_amdgcn_mfma_f32_16x16x32_bf16(
                        ak, aq[c], scv[ns], 0, 0, 0);
                }

            const bool diag = (kt == qt);
            const int ql = w * 16 + l16;
#pragma unroll
            for (int ns = 0; ns < 4; ns++) {
                float p[4];
#pragma unroll
                for (int r = 0; r < 4; r++) {
                    int key = ns * 16 + quad * 4 + r;
                    p[r] = (diag && key > ql) ? 0.f
                                              : __builtin_amdgcn_exp2f(scv[ns][r]);
                    lsum += p[r];
                }
                union { unsigned u[2]; bf4 v; } pk;
                pk.u[0] = (__float_as_uint(p[0]) >> 16) |
                          (__float_as_uint(p[1]) & 0xffff0000u);
                pk.u[1] = (__float_as_uint(p[2]) >> 16) |
                          (__float_as_uint(p[3]) & 0xffff0000u);
#pragma unroll
                for (int ds = 0; ds < 4; ds++) {
                    bf4 av = *(const bf4*)&Vs[ns >> 1][ds * 16 + l16]
                        [((((ns & 1) * 2 + (quad >> 1)) ^ swz) * 8) + (quad & 1) * 4];
                    oT[ds] = __builtin_amdgcn_mfma_f32_16x16x16bf16_1k(
                        av, pk.v, oT[ds], 0, 0, 0);
                }
            }
        }

        float l = lsum;
        l += __shfl_xor(l, 16, 64);
        l += __shfl_xor(l, 32, 64);
        const float inv = 1.f / l;
        const int qq = q0 + w * 16 + l16;
#pragma unroll
        for (int ds = 0; ds < 4; ds++) {
            u16 t4[4];
#pragma unroll
            for (int r = 0; r < 4; r++) t4[r] = f2bf(oT[ds][r] * inv);
            *(uint2*)(Og + base + (size_t)qq * DMODEL + ds * 16 + quad * 4) =
                *(uint2*)t4;
        }
    }
}

// ---------------------------------------------------------------------------
// Workspace: d_ws 32MB = wT(8) | qb(8) | kb(8) | ob(8).
// Transients xb/vt live inside d_out (16MB), dead before O-proj writes it.
// ---------------------------------------------------------------------------
extern "C" void kernel_launch(void* const* d_in, const int* in_sizes, int n_in,
                              void* d_out, int out_size, void* d_ws, size_t ws_size,
                              hipStream_t stream) {
    const float* x  = (const float*)d_in[0];
    const float* wq = (const float*)d_in[1];
    const float* bq = (const float*)d_in[2];
    const float* wk = (const float*)d_in[3];
    const float* bk = (const float*)d_in[4];
    const float* wv = (const float*)d_in[5];
    const float* bv = (const float*)d_in[6];
    const float* wo = (const float*)d_in[7];
    const float* bo = (const float*)d_in[8];
    float* out = (float*)d_out;

    const size_t E = (size_t)MROWS * DMODEL; // 4M elems
    u16* xb  = (u16*)d_out;      // bf16 x (dead after QKV GEMM)
    u16* vt  = xb + E;           // V^T (dead after attn)
    u16* wT  = (u16*)d_ws;       // wqT|wkT|wvT|woT
    u16* woT = wT + 3145728;
    u16* qb  = wT + 4194304;
    u16* kb  = qb + E;
    u16* ob  = kb + E;

    dim3 blk(256);
    prep_kernel<<<3072, blk, 0, stream>>>(x, xb, wq, wk, wv, wo, wT);

    // fused QKV: N=3072, Q scale = log2e/8, 64x128 tiles double-buffered
    gemm_mfma<0><<<dim3(24, 64), blk, 0, stream>>>(
        xb, wT, bq, bk, bv, qb, kb, vt, nullptr, 0.18033688011112042f);

    // XCD-locality grid: x = bh (32), y = paired q-tile (16)
    dim3 agrid(BATCH * NHEADS, 16);
    attn_kernel<<<agrid, blk, 0, stream>>>(qb, kb, vt, ob);

    // O-proj: 64x128 tiles double-buffered, fp32 float4 stores
    gemm_mfma<1><<<dim3(8, 64), blk, 0, stream>>>(
        ob, woT, bo, nullptr, nullptr, nullptr, nullptr, nullptr, out, 1.0f);
}